// Round 9
// baseline (2021.766 us; speedup 1.0000x reference)
//
#include <hip/hip_runtime.h>
#include <cmath>
#include <cstdint>

#define NT 256
#define EG0 1024          // grid for full-E passes
#define EGP 2048          // grid for edge_pool
#define EG1 256           // grid for compacted passes
#define MAX_ROUND 16
#define SCAN_T 32
#define SCAN_IPB (NT*SCAN_T)
#define SENT 0x80000000u  // -0.0f sentinel for "no edge touched this cell"

// ---------- bitmask helpers (coverage state lives in ~12.5KB -> L1-resident) ----------

__device__ __forceinline__ int getbit(const unsigned int* bm, int v){
  return (bm[v>>5]>>(v&31))&1u;
}
__device__ __forceinline__ void setbit(unsigned int* bm, int v){
  unsigned int m = 1u<<(v&31);
  if(!(bm[v>>5]&m)) atomicOr(&bm[v>>5], m);   // read-skip: monotone, benign race
}

// Block-aggregated stream compaction append: ONE global atomic per block-tile.
__device__ __forceinline__ int block_append(int* cursor, bool pred, int* s_w){
  int wid  = threadIdx.x >> 6;
  int lane = threadIdx.x & 63;
  unsigned long long m = __ballot(pred);
  int cnt = __popcll(m);
  if(lane==0) s_w[wid]=cnt;
  __syncthreads();
  if(threadIdx.x==0){
    int t0=s_w[0], t1=s_w[1], t2=s_w[2], t3=s_w[3];
    int tot=t0+t1+t2+t3;
    int base = tot ? atomicAdd(cursor, tot) : 0;
    s_w[0]=base; s_w[1]=base+t0; s_w[2]=base+t0+t1; s_w[3]=base+t0+t1+t2;
  }
  __syncthreads();
  int pos = s_w[wid] + __popcll(m & ((1ull<<lane)-1ull));
  __syncthreads();
  return pos;
}

// ---------- init ----------

__global__ void k_init(int* a, int* b, int n){
  int v = blockIdx.x*NT + threadIdx.x;
  if(v<n){ a[v]=v; b[v]=v; }
}

// fill only c*c cells (c known on device by now)
__global__ void k_fill_dense(float* dense, const int* scal, long CMsq){
  long c = scal[0];
  long M = c*c; if(M>CMsq) M=CMsq;
  long stride = (long)gridDim.x*NT;
  for(long i = (long)blockIdx.x*NT + threadIdx.x; i<M; i+=stride)
    ((unsigned int*)dense)[i] = SENT;
}

// ---------- round 0 (full edge arrays) ----------

__global__ void k_hop0(int* b, const int* __restrict__ row,
                       const int* __restrict__ col, int E){
  int stride = gridDim.x*NT;
  for(int e = blockIdx.x*NT + threadIdx.x; e<E; e+=stride){
    int s = row[e];
    if(s < b[col[e]]) atomicMin(&b[col[e]], s);
  }
}

__global__ void k_hop0f(int* a, const int* b, const int* __restrict__ row,
                        const int* __restrict__ col, int n, int E){
  int stride = gridDim.x*NT;
  int total = n + E;
  for(int i = blockIdx.x*NT + threadIdx.x; i<total; i+=stride){
    if(i<n){
      if(b[i] < a[i]) atomicMin(&a[i], b[i]);
    } else {
      int e = i-n;
      int s = b[row[e]];
      if(s < a[col[e]]) atomicMin(&a[col[e]], s);
    }
  }
}

// dil1: new-MIS rows seed d2 + cover bits for row & col
__global__ void k_dil0(const int* a, unsigned int* d2b, unsigned int* coverb,
                       const int* __restrict__ row, const int* __restrict__ col, int E){
  int stride = gridDim.x*NT;
  for(int e = blockIdx.x*NT + threadIdx.x; e<E; e+=stride){
    int r = row[e];
    if(a[r]==r){
      int cc = col[e];
      setbit(d2b,r);  setbit(coverb,r);
      setbit(d2b,cc); setbit(coverb,cc);
    }
  }
}

// dil2: cover[col] |= d2[row]   (d2 bit subsumes the new-MIS check: dil0 set it)
__global__ void k_dil20(const unsigned int* d2b, unsigned int* coverb,
                        const int* __restrict__ row, const int* __restrict__ col, int E){
  int stride = gridDim.x*NT;
  for(int e = blockIdx.x*NT + threadIdx.x; e<E; e+=stride){
    if(getbit(d2b,row[e])) setbit(coverb,col[e]);
  }
}

// finalize nodes + build U1 + compact edges -> LB + clear d2b for next round
__global__ void k_fincomp0(int* a, int* b, int* mis, unsigned int* coverb,
                           unsigned int* d2b, int nwords, int n,
                           const int* __restrict__ row, const int* __restrict__ col, int E,
                           int2* Ld, int* lcnt1, int* U1, int* rcnt0){
  __shared__ int s_w[4];
  long nth = (long)gridDim.x*NT;
  for(long base = (long)blockIdx.x*NT; base < n; base += nth){
    int v = (int)base + threadIdx.x;
    bool unc = false;
    if(v<n){
      int nw = (a[v]==v);
      int cov = getbit(coverb,v) | nw;
      if(nw){ mis[v]=1; setbit(coverb,v); }
      int val = cov ? n : v;
      a[v]=val; b[v]=val;
      unc = !cov;
    }
    int pos = block_append(rcnt0, unc, s_w);
    if(unc) U1[pos]=v;
  }
  for(long base = (long)blockIdx.x*NT; base < E; base += nth){
    int e = (int)base + threadIdx.x;
    bool keep=false; int2 ed;
    if(e<E){
      ed = make_int2(row[e], col[e]);
      keep = (!getbit(coverb,ed.x)) || (!getbit(coverb,ed.y));
    }
    int pos = block_append(lcnt1, keep, s_w);
    if(keep) Ld[pos]=ed;
  }
  int stride = gridDim.x*NT;
  for(int w = blockIdx.x*NT + threadIdx.x; w<nwords; w+=stride) d2b[w]=0;
}

// ---------- rounds >=1 (compacted list, frontier list, gated) ----------

__global__ void k_hop1(int* b, const int* a, const int2* L, const int* pE,
                       const int* gate){
  if(*gate==0) return;
  int E = *pE;
  int stride = gridDim.x*NT;
  for(int e = blockIdx.x*NT + threadIdx.x; e<E; e+=stride){
    int2 ed = L[e];
    int s = a[ed.x];
    if(s < b[ed.y]) atomicMin(&b[ed.y], s);
  }
}

__global__ void k_hop1f(int* a, const int* b, const int2* L, const int* pE,
                        const int* U, const int* pU, const int* gate){
  if(*gate==0) return;
  int E = *pE, un = *pU;
  int total = un + E;
  int stride = gridDim.x*NT;
  for(int i = blockIdx.x*NT + threadIdx.x; i<total; i+=stride){
    if(i<un){
      int u = U[i];
      if(b[u] < a[u]) atomicMin(&a[u], b[u]);
    } else {
      int2 ed = L[i-un];
      int s = b[ed.x];
      if(s < a[ed.y]) atomicMin(&a[ed.y], s);
    }
  }
}

__global__ void k_dil11(const int* a, unsigned int* d2b, unsigned int* coverb, int* mis,
                        const int2* L, const int* pE, const int* U, const int* pU,
                        const int* gate){
  if(*gate==0) return;
  int E = *pE, un = *pU;
  int total = un + E;
  int stride = gridDim.x*NT;
  for(int i = blockIdx.x*NT + threadIdx.x; i<total; i+=stride){
    if(i<un){
      int u = U[i];
      if(a[u]==u){ mis[u]=1; setbit(coverb,u); setbit(d2b,u); }
    } else {
      int2 ed = L[i-un];
      if(a[ed.x]==ed.x){
        setbit(d2b,ed.x); setbit(coverb,ed.x);
        setbit(d2b,ed.y); setbit(coverb,ed.y);
      }
    }
  }
}

__global__ void k_dil21(const unsigned int* d2b, unsigned int* coverb, const int2* L,
                        const int* pE, const int* gate){
  if(*gate==0) return;
  int E = *pE;
  int stride = gridDim.x*NT;
  for(int e = blockIdx.x*NT + threadIdx.x; e<E; e+=stride){
    int2 ed = L[e];
    if(getbit(d2b,ed.x)) setbit(coverb,ed.y);
  }
}

// finalize: reset endpoints from final cover; recompact U and L; clear d2b
__global__ void k_fincomp1(int* a, int* b, const unsigned int* coverb,
                           unsigned int* d2b, int nwords, int n,
                           const int2* Ls, const int* pE, int2* Ld, int* lcntD,
                           const int* Us, const int* pU, int* Ud, int* rcntD,
                           const int* gate){
  if(*gate==0) return;
  __shared__ int s_w[4];
  int E = *pE, un = *pU;
  long nth = (long)gridDim.x*NT;
  for(long base = (long)blockIdx.x*NT; base < un; base += nth){
    int i = (int)base + threadIdx.x;
    bool unc=false; int u=0;
    if(i<un){ u = Us[i]; unc = !getbit(coverb,u); }
    int pos = block_append(rcntD, unc, s_w);
    if(unc) Ud[pos]=u;
  }
  for(long base = (long)blockIdx.x*NT; base < E; base += nth){
    int e = (int)base + threadIdx.x;
    bool keep=false; int2 ed;
    if(e<E){
      ed = Ls[e];
      int cx = getbit(coverb,ed.x), cy = getbit(coverb,ed.y);
      int vx = cx ? n : ed.x;  a[ed.x]=vx; b[ed.x]=vx;
      int vy = cy ? n : ed.y;  a[ed.y]=vy; b[ed.y]=vy;
      keep = (!cx) || (!cy);
    }
    int pos = block_append(lcntD, keep, s_w);
    if(keep) Ld[pos]=ed;
  }
  int stride = gridDim.x*NT;
  for(int w = blockIdx.x*NT + threadIdx.x; w<nwords; w+=stride) d2b[w]=0;
}

// ---------- cluster phase ----------

__global__ void k_cluster_init(const int* mis, int* a, int* b, int n){
  int v = blockIdx.x*NT + threadIdx.x;
  if(v<n){ int m = mis[v] ? v : n; a[v]=m; b[v]=m; }
}

__global__ void k_chop1(int* b, const int* a, const int* __restrict__ row,
                        const int* __restrict__ col, int n, int E){
  int stride = gridDim.x*NT;
  for(int e = blockIdx.x*NT + threadIdx.x; e<E; e+=stride){
    int s = a[row[e]];
    if(s < n && s < b[col[e]]) atomicMin(&b[col[e]], s);
  }
}

__global__ void k_chop2f(int* a, const int* b, const int* __restrict__ row,
                         const int* __restrict__ col, int n, int E){
  int stride = gridDim.x*NT;
  int total = n + E;
  for(int i = blockIdx.x*NT + threadIdx.x; i<total; i+=stride){
    if(i<n){
      if(b[i] < a[i]) atomicMin(&a[i], b[i]);
    } else {
      int e = i-n;
      int s = b[row[e]];
      if(s < n && s < a[col[e]]) atomicMin(&a[col[e]], s);
    }
  }
}

__global__ void k_mark(const int* mr, const int* mis, int* present, int* cmis, int n){
  int v = blockIdx.x*NT + threadIdx.x;
  int m = 0;
  if(v<n){
    int r = mr[v];
    if(r<n) present[r]=1;
    m = mis[v];
  }
  __shared__ int sh[NT];
  sh[threadIdx.x]=m; __syncthreads();
  for(int off=NT/2; off>0; off>>=1){
    if(threadIdx.x<off) sh[threadIdx.x]+=sh[threadIdx.x+off];
    __syncthreads();
  }
  if(threadIdx.x==0 && sh[0]) atomicAdd(cmis, sh[0]);
}

// ---------- generic scan ----------

__global__ void k_scan1(const int* A, int M, int* bsum){
  int t = threadIdx.x;
  long base = (long)blockIdx.x*SCAN_IPB + (long)t*SCAN_T;
  int s = 0;
  #pragma unroll
  for(int j=0;j<SCAN_T;j++){ long i=base+j; if(i<M) s += A[i]; }
  __shared__ int sh[NT];
  sh[t]=s; __syncthreads();
  for(int off=NT/2; off>0; off>>=1){ if(t<off) sh[t]+=sh[t+off]; __syncthreads(); }
  if(t==0) bsum[blockIdx.x]=sh[0];
}

__global__ void k_scan2(const int* bsum, int* bscan, int B, int* totalOut){
  __shared__ int sh[NT];
  int t = threadIdx.x;
  int carry = 0;
  for(int base=0; base<B; base+=NT){
    int i = base+t;
    int v = (i<B) ? bsum[i] : 0;
    sh[t]=v; __syncthreads();
    for(int off=1; off<NT; off<<=1){
      int x=0; if(t>=off) x=sh[t-off];
      __syncthreads();
      sh[t]+=x; __syncthreads();
    }
    int incl = sh[t];
    if(i<B) bscan[i] = carry + incl - v;
    carry += sh[NT-1];
    __syncthreads();
  }
  if(t==0 && totalOut) *totalOut = carry;
}

__global__ void k_scan3(const int* A, int M, const int* bscan, int* pref){
  int t = threadIdx.x;
  long base = (long)blockIdx.x*SCAN_IPB + (long)t*SCAN_T;
  int s = 0;
  #pragma unroll
  for(int j=0;j<SCAN_T;j++){ long i=base+j; if(i<M) s += A[i]; }
  __shared__ int sh[NT];
  sh[t]=s; __syncthreads();
  for(int off=1; off<NT; off<<=1){
    int x=0; if(t>=off) x=sh[t-off];
    __syncthreads();
    sh[t]+=x; __syncthreads();
  }
  int run = bscan[blockIdx.x] + (sh[t]-s);
  for(int j=0;j<SCAN_T;j++){
    long i=base+j;
    if(i<M){ pref[i]=run; run += A[i]; }
  }
}

// ---------- clustering & pooling ----------

__global__ void k_assign(const int* mr, const int* pref, int* cl, int* ccount, int n){
  int v = blockIdx.x*NT + threadIdx.x;
  if(v<n){
    int r = mr[v];
    int cid = (r<n) ? pref[r] : 0;
    cl[v]=cid;
    atomicAdd(&ccount[cid],1);
  }
}

__global__ void k_scatter_nodes(const int* cl, const int* cstart, int* cursor, int* nodeList, int n){
  int v = blockIdx.x*NT + threadIdx.x;
  if(v<n){
    int cid = cl[v];
    int pos = cstart[cid] + atomicAdd(&cursor[cid],1);
    nodeList[pos]=v;
  }
}

__global__ void k_pool_x(const float* __restrict__ x, const int* nodeList, const int* cstart,
                         const int* ccount, const int* scal, float* out, long out_size){
  int c = scal[0], U = scal[1];
  int t = threadIdx.x;
  for(int cid=blockIdx.x; cid<c; cid+=gridDim.x){
    float s0=0.f, s1=0.f, s2=0.f, s3=0.f;
    if(cid<U){
      int st = cstart[cid], cn = ccount[cid];
      int i=0;
      for(; i+3<cn; i+=4){
        int n0=nodeList[st+i], n1=nodeList[st+i+1], n2=nodeList[st+i+2], n3=nodeList[st+i+3];
        s0 += x[(size_t)n0*256 + t];
        s1 += x[(size_t)n1*256 + t];
        s2 += x[(size_t)n2*256 + t];
        s3 += x[(size_t)n3*256 + t];
      }
      for(; i<cn; i++) s0 += x[(size_t)nodeList[st+i]*256 + t];
      s0 += s1+s2+s3;
    }
    long idx = (long)cid*256 + t;
    if(idx < out_size) out[idx]=s0;
  }
}

// one fp32 atomic per edge; presence = bit pattern != SENT (-0.0 + x == x)
__global__ void k_edge_pool(const int* __restrict__ row, const int* __restrict__ col,
                            const float* __restrict__ attr, const int* cl,
                            const int* scal, float* dense, int E, long CMsq){
  int c = scal[0];
  int stride = gridDim.x*NT;
  for(int e = blockIdx.x*NT + threadIdx.x; e<E; e+=stride){
    long key = (long)cl[row[e]]*c + cl[col[e]];
    if(key < CMsq){
      unsafeAtomicAdd(&dense[key], attr[e]);
    }
  }
}

__device__ __forceinline__ int cellp(const float* dense, long i){
  return __float_as_uint(dense[i]) != SENT;
}

__global__ void k_cscan1(const float* dense, const int* scal, int* bsum, long CMsq){
  int c = scal[0];
  long M = (long)c*c; if(M>CMsq) M=CMsq;
  int t = threadIdx.x;
  long base = (long)blockIdx.x*SCAN_IPB + (long)t*SCAN_T;
  int s = 0;
  if(base < M && c > 0){
    int r = (int)(base / c);
    int q = (int)(base - (long)r*c);
    for(int j=0;j<SCAN_T;j++){
      long i=base+j;
      if(i<M){
        if(cellp(dense,i) && r!=q) s++;
      }
      if(++q==c){ q=0; r++; }
    }
  }
  __shared__ int sh[NT];
  sh[t]=s; __syncthreads();
  for(int off=NT/2; off>0; off>>=1){ if(t<off) sh[t]+=sh[t+off]; __syncthreads(); }
  if(t==0) bsum[blockIdx.x]=sh[0];
}

__global__ void k_cemit(const float* dense, const int* scal,
                        const int* bscan, float* out, long out_size, long CMsq){
  int c = scal[0]; int P = scal[2];
  long M = (long)c*c; if(M>CMsq) M=CMsq;
  long xoff = (long)c*256;
  int t = threadIdx.x;
  long base = (long)blockIdx.x*SCAN_IPB + (long)t*SCAN_T;
  int s = 0;
  int r0=0,q0=0;
  if(base < M && c > 0){
    r0 = (int)(base / c);
    q0 = (int)(base - (long)r0*c);
    int r=r0, q=q0;
    for(int j=0;j<SCAN_T;j++){
      long i=base+j;
      if(i<M){
        if(cellp(dense,i) && r!=q) s++;
      }
      if(++q==c){ q=0; r++; }
    }
  }
  __shared__ int sh[NT];
  sh[t]=s; __syncthreads();
  for(int off=1; off<NT; off<<=1){
    int x=0; if(t>=off) x=sh[t-off];
    __syncthreads();
    sh[t]+=x; __syncthreads();
  }
  int run = bscan[blockIdx.x] + (sh[t]-s);
  if(base < M && c > 0){
    int r=r0, q=q0;
    for(int j=0;j<SCAN_T;j++){
      long i=base+j;
      if(i<M && cellp(dense,i) && r!=q){
        long o0 = xoff + run;
        long o1 = xoff + (long)P + run;
        long o2 = xoff + 2L*(long)P + run;
        if(o0<out_size) out[o0]=(float)r;
        if(o1<out_size) out[o1]=(float)q;
        if(o2<out_size) out[o2]=dense[i];
        run++;
      }
      if(++q==c){ q=0; r++; }
    }
  }
}

// ---------- host ----------

extern "C" void kernel_launch(void* const* d_in, const int* in_sizes, int n_in,
                              void* d_out, int out_size, void* d_ws, size_t ws_size,
                              hipStream_t stream){
  (void)n_in;
  const float* x     = (const float*)d_in[0];
  const int*   eidx  = (const int*)d_in[1];
  const float* eattr = (const float*)d_in[2];
  const int D = 256;
  int n = in_sizes[0]/D;
  int E = in_sizes[1]/2;
  const int* row = eidx;
  const int* col = eidx + E;
  int nwords = (n+31)>>5;

  char* p = (char*)d_ws;
  auto alloc = [&](size_t bytes)->char*{ char* r=p; p += (bytes+255)&~(size_t)255; return r; };
  int2* LA   = (int2*)alloc((size_t)E*8);
  int2* LB   = (int2*)alloc((size_t)E*8);
  int* a     = (int*)alloc((size_t)n*4);
  int* b     = (int*)alloc((size_t)n*4);
  int* cl    = (int*)alloc((size_t)n*4);
  int* nodeList = (int*)alloc((size_t)n*4);
  int* pref  = (int*)alloc((size_t)n*4);
  int* U1    = (int*)alloc((size_t)n*4);
  int* U2    = (int*)alloc((size_t)n*4);
  int* bsum  = (int*)alloc(4096*4);
  int* bscan = (int*)alloc(4096*4);
  char* zstart = p;                         // zeroed each call
  int* mis     = (int*)alloc((size_t)n*4);
  unsigned int* coverb = (unsigned int*)alloc((size_t)nwords*4);
  unsigned int* d2b    = (unsigned int*)alloc((size_t)nwords*4);
  int* present = (int*)alloc((size_t)n*4);
  int* ccount  = (int*)alloc((size_t)n*4);
  int* cursor  = (int*)alloc((size_t)n*4);
  int* rcnt    = (int*)alloc((MAX_ROUND+2)*4);
  int* lcnt    = (int*)alloc((MAX_ROUND+2)*4);
  int* scal    = (int*)alloc(64);              // [0]=c, [1]=U, [2]=P
  size_t zbytes = (size_t)(p - zstart);

  size_t used   = (size_t)(p-(char*)d_ws);
  size_t remain = (ws_size > used+4096) ? ws_size-used-4096 : 0;
  size_t cells  = remain/4;
  long CM = (long)std::sqrt((double)cells);
  while(CM>1 && CM*CM > (long)cells) CM--;
  if(CM>4096) CM=4096;
  if(CM<1) CM=1;
  long CMsq = CM*CM;
  float* dense = (float*)alloc((size_t)CMsq*4);

  hipMemsetAsync(zstart, 0, zbytes, stream);

  int NB  = (n+NT-1)/NT;
  int NBs = (n+SCAN_IPB-1)/SCAN_IPB;
  int CB  = (int)((CMsq+SCAN_IPB-1)/SCAN_IPB);

  // ---- round 0 (full graph) ----
  k_init    <<<NB,NT,0,stream>>>(a,b,n);
  k_hop0    <<<EG0,NT,0,stream>>>(b,row,col,E);
  k_hop0f   <<<EG0,NT,0,stream>>>(a,b,row,col,n,E);
  k_dil0    <<<EG0,NT,0,stream>>>(a,d2b,coverb,row,col,E);
  k_dil20   <<<EG0,NT,0,stream>>>(d2b,coverb,row,col,E);
  k_fincomp0<<<EG0,NT,0,stream>>>(a,b,mis,coverb,d2b,nwords,n,row,col,E,LB,&lcnt[1],U1,&rcnt[0]);

  // ---- rounds 1..MAX_ROUND-1 (compacted, gated on rcnt[r-1]) ----
  for(int r=1; r<MAX_ROUND; ++r){
    int2* Ls = (r&1) ? LB : LA;
    int2* Ld = (r&1) ? LA : LB;
    int*  Us = (r&1) ? U1 : U2;
    int*  Ud = (r&1) ? U2 : U1;
    k_hop1    <<<EG1,NT,0,stream>>>(b,a,Ls,&lcnt[r],&rcnt[r-1]);
    k_hop1f   <<<EG1,NT,0,stream>>>(a,b,Ls,&lcnt[r],Us,&rcnt[r-1],&rcnt[r-1]);
    k_dil11   <<<EG1,NT,0,stream>>>(a,d2b,coverb,mis,Ls,&lcnt[r],Us,&rcnt[r-1],&rcnt[r-1]);
    k_dil21   <<<EG1,NT,0,stream>>>(d2b,coverb,Ls,&lcnt[r],&rcnt[r-1]);
    k_fincomp1<<<EG1,NT,0,stream>>>(a,b,coverb,d2b,nwords,n,Ls,&lcnt[r],Ld,&lcnt[r+1],
                                    Us,&rcnt[r-1],Ud,&rcnt[r],&rcnt[r-1]);
  }

  // ---- cluster propagation ----
  k_cluster_init<<<NB,NT,0,stream>>>(mis,a,b,n);
  k_chop1 <<<EG0,NT,0,stream>>>(b,a,row,col,n,E);
  k_chop2f<<<EG0,NT,0,stream>>>(a,b,row,col,n,E);

  // ---- unique -> cluster ids ----
  k_mark <<<NB,NT,0,stream>>>(a,mis,present,scal,n);
  k_scan1<<<NBs,NT,0,stream>>>(present,n,bsum);
  k_scan2<<<1,NT,0,stream>>>(bsum,bscan,NBs,scal+1);
  k_scan3<<<NBs,NT,0,stream>>>(present,n,bscan,pref);
  k_assign<<<NB,NT,0,stream>>>(a,pref,cl,ccount,n);

  // ---- fill dense (c now known on device) ----
  k_fill_dense<<<2048,NT,0,stream>>>(dense,scal,CMsq);

  // ---- counting sort by cluster ----
  k_scan1<<<NBs,NT,0,stream>>>(ccount,n,bsum);
  k_scan2<<<1,NT,0,stream>>>(bsum,bscan,NBs,nullptr);
  k_scan3<<<NBs,NT,0,stream>>>(ccount,n,bscan,pref);
  k_scatter_nodes<<<NB,NT,0,stream>>>(cl,pref,cursor,nodeList,n);

  // ---- x_pooled ----
  k_pool_x<<<1024,NT,0,stream>>>(x,nodeList,pref,ccount,scal,(float*)d_out,(long)out_size);

  // ---- pooled adjacency ----
  k_edge_pool<<<EGP,NT,0,stream>>>(row,col,eattr,cl,scal,dense,E,CMsq);
  k_cscan1<<<CB,NT,0,stream>>>(dense,scal,bsum,CMsq);
  k_scan2 <<<1,NT,0,stream>>>(bsum,bscan,CB,scal+2);
  k_cemit <<<CB,NT,0,stream>>>(dense,scal,bscan,(float*)d_out,(long)out_size,CMsq);
}

// Round 10
// 1933.221 us; speedup vs baseline: 1.0458x; 1.0458x over previous
//
#include <hip/hip_runtime.h>
#include <cmath>
#include <cstdint>

#define NT 256
#define EG0 1024          // grid for full-E passes
#define EG1 256           // grid for compacted passes
#define MAX_ROUND 16
#define SCAN_T 32
#define SCAN_IPB (NT*SCAN_T)
#define SENT 0x80000000u  // -0.0f sentinel for "no edge touched this cell"

// ---------- helpers ----------

__device__ __forceinline__ int getbit(const unsigned int* bm, int v){
  return (bm[v>>5]>>(v&31))&1u;
}
__device__ __forceinline__ void setbit(unsigned int* bm, int v){
  unsigned int m = 1u<<(v&31);
  if(!(bm[v>>5]&m)) atomicOr(&bm[v>>5], m);   // rare-set, read-mostly usage only
}

// Block-aggregated stream compaction append: ONE global atomic per block-tile.
__device__ __forceinline__ int block_append(int* cursor, bool pred, int* s_w){
  int wid  = threadIdx.x >> 6;
  int lane = threadIdx.x & 63;
  unsigned long long m = __ballot(pred);
  int cnt = __popcll(m);
  if(lane==0) s_w[wid]=cnt;
  __syncthreads();
  if(threadIdx.x==0){
    int t0=s_w[0], t1=s_w[1], t2=s_w[2], t3=s_w[3];
    int tot=t0+t1+t2+t3;
    int base = tot ? atomicAdd(cursor, tot) : 0;
    s_w[0]=base; s_w[1]=base+t0; s_w[2]=base+t0+t1; s_w[3]=base+t0+t1+t2;
  }
  __syncthreads();
  int pos = s_w[wid] + __popcll(m & ((1ull<<lane)-1ull));
  __syncthreads();
  return pos;
}

// ---------- init ----------

__global__ void k_init(int* a, int* b, int n){
  int v = blockIdx.x*NT + threadIdx.x;
  if(v<n){ a[v]=v; b[v]=v; }
}

__global__ void k_fill_dense(float* dense, const int* scal, long CMsq){
  long c = scal[0];
  long M = c*c; if(M>CMsq) M=CMsq;
  long stride = (long)gridDim.x*NT;
  for(long i = (long)blockIdx.x*NT + threadIdx.x; i<M; i+=stride)
    ((unsigned int*)dense)[i] = SENT;
}

// ---------- round 0 (full edge arrays) ----------

__global__ void k_hop0(int* b, const int* __restrict__ row,
                       const int* __restrict__ col, int E){
  int stride = gridDim.x*NT;
  for(int e = blockIdx.x*NT + threadIdx.x; e<E; e+=stride){
    int s = row[e];
    if(s < b[col[e]]) atomicMin(&b[col[e]], s);
  }
}

__global__ void k_hop0f(int* a, const int* b, const int* __restrict__ row,
                        const int* __restrict__ col, int n, int E){
  int stride = gridDim.x*NT;
  int total = n + E;
  for(int i = blockIdx.x*NT + threadIdx.x; i<total; i+=stride){
    if(i<n){
      if(b[i] < a[i]) atomicMin(&a[i], b[i]);
    } else {
      int e = i-n;
      int s = b[row[e]];
      if(s < a[col[e]]) atomicMin(&a[col[e]], s);
    }
  }
}

// dil1: new-MIS rows seed d2 (epoch) + cover; PLAIN STORES (benign races)
__global__ void k_dil0(const int* a, int* d2, int* cover, const int* __restrict__ row,
                       const int* __restrict__ col, int E, int ep){
  int stride = gridDim.x*NT;
  for(int e = blockIdx.x*NT + threadIdx.x; e<E; e+=stride){
    int r = row[e];
    if(a[r]==r){
      int cc = col[e];
      d2[r]=ep;  cover[r]=1;
      d2[cc]=ep; cover[cc]=1;
    }
  }
}

__global__ void k_dil20(const int* a, const int* d2, int* cover, const int* __restrict__ row,
                        const int* __restrict__ col, int E, int ep){
  int stride = gridDim.x*NT;
  for(int e = blockIdx.x*NT + threadIdx.x; e<E; e+=stride){
    int r = row[e];
    if((d2[r]==ep || a[r]==r) && !cover[col[e]]) cover[col[e]]=1;
  }
}

// finalize nodes + build U1 + compact edges -> LB (runs AFTER cover settled)
__global__ void k_fincomp0(int* a, int* b, unsigned int* misb, int* cover, int n,
                           const int* __restrict__ row, const int* __restrict__ col, int E,
                           int2* Ld, int* lcnt1, int* U1, int* rcnt0){
  __shared__ int s_w[4];
  long nth = (long)gridDim.x*NT;
  for(long base = (long)blockIdx.x*NT; base < n; base += nth){
    int v = (int)base + threadIdx.x;
    bool unc = false;
    if(v<n){
      int nw = (a[v]==v);
      if(nw){ setbit(misb,v); if(!cover[v]) cover[v]=1; }
      int cov = cover[v] | nw;
      int val = cov ? n : v;
      a[v]=val; b[v]=val;
      unc = !cov;
    }
    int pos = block_append(rcnt0, unc, s_w);
    if(unc) U1[pos]=v;
  }
  for(long base = (long)blockIdx.x*NT; base < E; base += nth){
    int e = (int)base + threadIdx.x;
    bool keep=false; int2 ed;
    if(e<E){
      ed = make_int2(row[e], col[e]);
      keep = (!cover[ed.x]) || (!cover[ed.y]);
    }
    int pos = block_append(lcnt1, keep, s_w);
    if(keep) Ld[pos]=ed;
  }
}

// ---------- rounds >=1 (compacted list, frontier list, gated) ----------

__global__ void k_hop1(int* b, const int* a, const int2* L, const int* pE,
                       const int* gate){
  if(*gate==0) return;
  int E = *pE;
  int stride = gridDim.x*NT;
  for(int e = blockIdx.x*NT + threadIdx.x; e<E; e+=stride){
    int2 ed = L[e];
    int s = a[ed.x];
    if(s < b[ed.y]) atomicMin(&b[ed.y], s);
  }
}

__global__ void k_hop1f(int* a, const int* b, const int2* L, const int* pE,
                        const int* U, const int* pU, const int* gate){
  if(*gate==0) return;
  int E = *pE, un = *pU;
  int total = un + E;
  int stride = gridDim.x*NT;
  for(int i = blockIdx.x*NT + threadIdx.x; i<total; i+=stride){
    if(i<un){
      int u = U[i];
      if(b[u] < a[u]) atomicMin(&a[u], b[u]);
    } else {
      int2 ed = L[i-un];
      int s = b[ed.x];
      if(s < a[ed.y]) atomicMin(&a[ed.y], s);
    }
  }
}

__global__ void k_dil11(const int* a, int* d2, int* cover, unsigned int* misb,
                        const int2* L, const int* pE, const int* U, const int* pU,
                        const int* gate, int ep){
  if(*gate==0) return;
  int E = *pE, un = *pU;
  int total = un + E;
  int stride = gridDim.x*NT;
  for(int i = blockIdx.x*NT + threadIdx.x; i<total; i+=stride){
    if(i<un){
      int u = U[i];
      if(a[u]==u){ setbit(misb,u); cover[u]=1; d2[u]=ep; }
    } else {
      int2 ed = L[i-un];
      if(a[ed.x]==ed.x){ d2[ed.x]=ep; cover[ed.x]=1; d2[ed.y]=ep; cover[ed.y]=1; }
    }
  }
}

__global__ void k_dil21(const int* a, const int* d2, int* cover, const int2* L,
                        const int* pE, const int* gate, int ep){
  if(*gate==0) return;
  int E = *pE;
  int stride = gridDim.x*NT;
  for(int e = blockIdx.x*NT + threadIdx.x; e<E; e+=stride){
    int2 ed = L[e];
    if((d2[ed.x]==ep || a[ed.x]==ed.x) && !cover[ed.y]) cover[ed.y]=1;
  }
}

// finalize: reset endpoints from final cover; recompact U and L (ping-pong)
__global__ void k_fincomp1(int* a, int* b, const int* cover, int n,
                           const int2* Ls, const int* pE, int2* Ld, int* lcntD,
                           const int* Us, const int* pU, int* Ud, int* rcntD,
                           const int* gate){
  if(*gate==0) return;
  __shared__ int s_w[4];
  int E = *pE, un = *pU;
  long nth = (long)gridDim.x*NT;
  for(long base = (long)blockIdx.x*NT; base < un; base += nth){
    int i = (int)base + threadIdx.x;
    bool unc=false; int u=0;
    if(i<un){ u = Us[i]; unc = !cover[u]; }
    int pos = block_append(rcntD, unc, s_w);
    if(unc) Ud[pos]=u;
  }
  for(long base = (long)blockIdx.x*NT; base < E; base += nth){
    int e = (int)base + threadIdx.x;
    bool keep=false; int2 ed;
    if(e<E){
      ed = Ls[e];
      int vx = cover[ed.x] ? n : ed.x;  a[ed.x]=vx; b[ed.x]=vx;
      int vy = cover[ed.y] ? n : ed.y;  a[ed.y]=vy; b[ed.y]=vy;
      keep = (!cover[ed.x]) || (!cover[ed.y]);
    }
    int pos = block_append(lcntD, keep, s_w);
    if(keep) Ld[pos]=ed;
  }
}

// ---------- cluster phase (bitmask-filtered: sets rare, reads dominate) ----------

__global__ void k_cluster_init(const unsigned int* misb, unsigned int* reach1b,
                               int* a, int* b, int n){
  int v = blockIdx.x*NT + threadIdx.x;
  if(v<n){
    int m = getbit(misb,v);
    int val = m ? v : n;
    a[v]=val; b[v]=val;
    if(m) setbit(reach1b,v);
  }
}

// hop1: only MIS rows contribute; value == row index. misb read is L1-resident.
__global__ void k_chop1(int* b, const unsigned int* misb, unsigned int* reach1b,
                        const int* __restrict__ row, const int* __restrict__ col, int E){
  int stride = gridDim.x*NT;
  for(int e = blockIdx.x*NT + threadIdx.x; e<E; e+=stride){
    int r = row[e];
    if(getbit(misb,r)){
      int cc = col[e];
      if(r < b[cc]) atomicMin(&b[cc], r);
      setbit(reach1b, cc);
    }
  }
}

// hop2 + self-fold; edge phase filtered by reach1b (only ~10% of rows have b<n)
__global__ void k_chop2f(int* a, const int* b, const unsigned int* reach1b,
                         const int* __restrict__ row, const int* __restrict__ col,
                         int n, int E){
  int stride = gridDim.x*NT;
  int total = n + E;
  for(int i = blockIdx.x*NT + threadIdx.x; i<total; i+=stride){
    if(i<n){
      if(b[i] < a[i]) atomicMin(&a[i], b[i]);
    } else {
      int e = i-n;
      int r = row[e];
      if(getbit(reach1b,r)){
        int s = b[r];
        if(s < n && s < a[col[e]]) atomicMin(&a[col[e]], s);
      }
    }
  }
}

__global__ void k_mark(const int* mr, const unsigned int* misb, int* present, int* cmis, int n){
  int v = blockIdx.x*NT + threadIdx.x;
  int m = 0;
  if(v<n){
    int r = mr[v];
    if(r<n && !present[r]) present[r]=1;   // read-filter: c effective stores
    m = getbit(misb,v);
  }
  __shared__ int sh[NT];
  sh[threadIdx.x]=m; __syncthreads();
  for(int off=NT/2; off>0; off>>=1){
    if(threadIdx.x<off) sh[threadIdx.x]+=sh[threadIdx.x+off];
    __syncthreads();
  }
  if(threadIdx.x==0 && sh[0]) atomicAdd(cmis, sh[0]);
}

// ---------- generic scan ----------

__global__ void k_scan1(const int* A, int M, int* bsum){
  int t = threadIdx.x;
  long base = (long)blockIdx.x*SCAN_IPB + (long)t*SCAN_T;
  int s = 0;
  #pragma unroll
  for(int j=0;j<SCAN_T;j++){ long i=base+j; if(i<M) s += A[i]; }
  __shared__ int sh[NT];
  sh[t]=s; __syncthreads();
  for(int off=NT/2; off>0; off>>=1){ if(t<off) sh[t]+=sh[t+off]; __syncthreads(); }
  if(t==0) bsum[blockIdx.x]=sh[0];
}

__global__ void k_scan2(const int* bsum, int* bscan, int B, int* totalOut){
  __shared__ int sh[NT];
  int t = threadIdx.x;
  int carry = 0;
  for(int base=0; base<B; base+=NT){
    int i = base+t;
    int v = (i<B) ? bsum[i] : 0;
    sh[t]=v; __syncthreads();
    for(int off=1; off<NT; off<<=1){
      int x=0; if(t>=off) x=sh[t-off];
      __syncthreads();
      sh[t]+=x; __syncthreads();
    }
    int incl = sh[t];
    if(i<B) bscan[i] = carry + incl - v;
    carry += sh[NT-1];
    __syncthreads();
  }
  if(t==0 && totalOut) *totalOut = carry;
}

__global__ void k_scan3(const int* A, int M, const int* bscan, int* pref){
  int t = threadIdx.x;
  long base = (long)blockIdx.x*SCAN_IPB + (long)t*SCAN_T;
  int s = 0;
  #pragma unroll
  for(int j=0;j<SCAN_T;j++){ long i=base+j; if(i<M) s += A[i]; }
  __shared__ int sh[NT];
  sh[t]=s; __syncthreads();
  for(int off=1; off<NT; off<<=1){
    int x=0; if(t>=off) x=sh[t-off];
    __syncthreads();
    sh[t]+=x; __syncthreads();
  }
  int run = bscan[blockIdx.x] + (sh[t]-s);
  for(int j=0;j<SCAN_T;j++){
    long i=base+j;
    if(i<M){ pref[i]=run; run += A[i]; }
  }
}

// ---------- clustering & pooling ----------

__global__ void k_assign(const int* mr, const int* pref, int* cl, int* ccount, int n){
  int v = blockIdx.x*NT + threadIdx.x;
  if(v<n){
    int r = mr[v];
    int cid = (r<n) ? pref[r] : 0;
    cl[v]=cid;
    atomicAdd(&ccount[cid],1);
  }
}

__global__ void k_scatter_nodes(const int* cl, const int* cstart, int* cursor, int* nodeList, int n){
  int v = blockIdx.x*NT + threadIdx.x;
  if(v<n){
    int cid = cl[v];
    int pos = cstart[cid] + atomicAdd(&cursor[cid],1);
    nodeList[pos]=v;
  }
}

// 1024 threads: 4 node-groups x 256 dims, LDS reduce
__global__ void __launch_bounds__(1024)
k_pool_x(const float* __restrict__ x, const int* nodeList, const int* cstart,
         const int* ccount, const int* scal, float* out, long out_size){
  __shared__ float sh[4][256];
  int c = scal[0], U = scal[1];
  int t = threadIdx.x & 255;
  int g = threadIdx.x >> 8;
  for(int cid=blockIdx.x; cid<c; cid+=gridDim.x){
    float s = 0.f;
    if(cid<U){
      int st = cstart[cid], cn = ccount[cid];
      for(int i=g; i<cn; i+=4)
        s += x[(size_t)nodeList[st+i]*256 + t];
    }
    sh[g][t]=s;
    __syncthreads();
    if(g==0){
      long idx = (long)cid*256 + t;
      if(idx < out_size) out[idx] = sh[0][t]+sh[1][t]+sh[2][t]+sh[3][t];
    }
    __syncthreads();
  }
}

// one fp32 atomic per edge; presence = bit pattern != SENT (-0.0 + x == x)
__global__ void k_edge_pool(const int* __restrict__ row, const int* __restrict__ col,
                            const float* __restrict__ attr, const int* cl,
                            const int* scal, float* dense, int E, long CMsq){
  int c = scal[0];
  int stride = gridDim.x*NT;
  for(int e = blockIdx.x*NT + threadIdx.x; e<E; e+=stride){
    long key = (long)cl[row[e]]*c + cl[col[e]];
    if(key < CMsq){
      unsafeAtomicAdd(&dense[key], attr[e]);
    }
  }
}

__device__ __forceinline__ int cellp(const float* dense, long i){
  return __float_as_uint(dense[i]) != SENT;
}

__global__ void k_cscan1(const float* dense, const int* scal, int* bsum, long CMsq){
  int c = scal[0];
  long M = (long)c*c; if(M>CMsq) M=CMsq;
  int t = threadIdx.x;
  long base = (long)blockIdx.x*SCAN_IPB + (long)t*SCAN_T;
  int s = 0;
  if(base < M && c > 0){
    int r = (int)(base / c);
    int q = (int)(base - (long)r*c);
    for(int j=0;j<SCAN_T;j++){
      long i=base+j;
      if(i<M){
        if(cellp(dense,i) && r!=q) s++;
      }
      if(++q==c){ q=0; r++; }
    }
  }
  __shared__ int sh[NT];
  sh[t]=s; __syncthreads();
  for(int off=NT/2; off>0; off>>=1){ if(t<off) sh[t]+=sh[t+off]; __syncthreads(); }
  if(t==0) bsum[blockIdx.x]=sh[0];
}

__global__ void k_cemit(const float* dense, const int* scal,
                        const int* bscan, float* out, long out_size, long CMsq){
  int c = scal[0]; int P = scal[2];
  long M = (long)c*c; if(M>CMsq) M=CMsq;
  long xoff = (long)c*256;
  int t = threadIdx.x;
  long base = (long)blockIdx.x*SCAN_IPB + (long)t*SCAN_T;
  int s = 0;
  int r0=0,q0=0;
  if(base < M && c > 0){
    r0 = (int)(base / c);
    q0 = (int)(base - (long)r0*c);
    int r=r0, q=q0;
    for(int j=0;j<SCAN_T;j++){
      long i=base+j;
      if(i<M){
        if(cellp(dense,i) && r!=q) s++;
      }
      if(++q==c){ q=0; r++; }
    }
  }
  __shared__ int sh[NT];
  sh[t]=s; __syncthreads();
  for(int off=1; off<NT; off<<=1){
    int x=0; if(t>=off) x=sh[t-off];
    __syncthreads();
    sh[t]+=x; __syncthreads();
  }
  int run = bscan[blockIdx.x] + (sh[t]-s);
  if(base < M && c > 0){
    int r=r0, q=q0;
    for(int j=0;j<SCAN_T;j++){
      long i=base+j;
      if(i<M && cellp(dense,i) && r!=q){
        long o0 = xoff + run;
        long o1 = xoff + (long)P + run;
        long o2 = xoff + 2L*(long)P + run;
        if(o0<out_size) out[o0]=(float)r;
        if(o1<out_size) out[o1]=(float)q;
        if(o2<out_size) out[o2]=dense[i];
        run++;
      }
      if(++q==c){ q=0; r++; }
    }
  }
}

// ---------- host ----------

extern "C" void kernel_launch(void* const* d_in, const int* in_sizes, int n_in,
                              void* d_out, int out_size, void* d_ws, size_t ws_size,
                              hipStream_t stream){
  (void)n_in;
  const float* x     = (const float*)d_in[0];
  const int*   eidx  = (const int*)d_in[1];
  const float* eattr = (const float*)d_in[2];
  const int D = 256;
  int n = in_sizes[0]/D;
  int E = in_sizes[1]/2;
  const int* row = eidx;
  const int* col = eidx + E;
  int nwords = (n+31)>>5;
  int CU_B = out_size/256 + 1; if(CU_B > n) CU_B = n;   // >= c (out has c*256 + 3P)

  char* p = (char*)d_ws;
  auto alloc = [&](size_t bytes)->char*{ char* r=p; p += (bytes+255)&~(size_t)255; return r; };
  int2* LA   = (int2*)alloc((size_t)E*8);
  int2* LB   = (int2*)alloc((size_t)E*8);
  int* a     = (int*)alloc((size_t)n*4);
  int* b     = (int*)alloc((size_t)n*4);
  int* cl    = (int*)alloc((size_t)n*4);
  int* nodeList = (int*)alloc((size_t)n*4);
  int* pref  = (int*)alloc((size_t)n*4);
  int* U1    = (int*)alloc((size_t)n*4);
  int* U2    = (int*)alloc((size_t)n*4);
  int* bsum  = (int*)alloc(4096*4);
  int* bscan = (int*)alloc(4096*4);
  char* zstart = p;                         // zeroed each call
  int* cover   = (int*)alloc((size_t)n*4);
  int* d2      = (int*)alloc((size_t)n*4);
  unsigned int* misb    = (unsigned int*)alloc((size_t)nwords*4);
  unsigned int* reach1b = (unsigned int*)alloc((size_t)nwords*4);
  int* present = (int*)alloc((size_t)n*4);
  int* ccount  = (int*)alloc((size_t)n*4);
  int* cursor  = (int*)alloc((size_t)n*4);
  int* rcnt    = (int*)alloc((MAX_ROUND+2)*4);
  int* lcnt    = (int*)alloc((MAX_ROUND+2)*4);
  int* scal    = (int*)alloc(64);              // [0]=c, [1]=U, [2]=P
  size_t zbytes = (size_t)(p - zstart);

  size_t used   = (size_t)(p-(char*)d_ws);
  size_t remain = (ws_size > used+4096) ? ws_size-used-4096 : 0;
  size_t cells  = remain/4;
  long CM = (long)std::sqrt((double)cells);
  while(CM>1 && CM*CM > (long)cells) CM--;
  if(CM>4096) CM=4096;
  if(CM<1) CM=1;
  long CMsq = CM*CM;
  float* dense = (float*)alloc((size_t)CMsq*4);

  hipMemsetAsync(zstart, 0, zbytes, stream);

  int NB  = (n+NT-1)/NT;
  int NBs = (n+SCAN_IPB-1)/SCAN_IPB;
  int NBc = (CU_B+SCAN_IPB-1)/SCAN_IPB;
  int CB  = (int)((CMsq+SCAN_IPB-1)/SCAN_IPB);

  // ---- round 0 (full graph) ----
  k_init    <<<NB,NT,0,stream>>>(a,b,n);
  k_hop0    <<<EG0,NT,0,stream>>>(b,row,col,E);
  k_hop0f   <<<EG0,NT,0,stream>>>(a,b,row,col,n,E);
  k_dil0    <<<EG0,NT,0,stream>>>(a,d2,cover,row,col,E,1);
  k_dil20   <<<EG0,NT,0,stream>>>(a,d2,cover,row,col,E,1);
  k_fincomp0<<<EG0,NT,0,stream>>>(a,b,misb,cover,n,row,col,E,LB,&lcnt[1],U1,&rcnt[0]);

  // ---- rounds 1..MAX_ROUND-1 (compacted, gated on rcnt[r-1]) ----
  for(int r=1; r<MAX_ROUND; ++r){
    int2* Ls = (r&1) ? LB : LA;
    int2* Ld = (r&1) ? LA : LB;
    int*  Us = (r&1) ? U1 : U2;
    int*  Ud = (r&1) ? U2 : U1;
    int ep = r+1;
    k_hop1    <<<EG1,NT,0,stream>>>(b,a,Ls,&lcnt[r],&rcnt[r-1]);
    k_hop1f   <<<EG1,NT,0,stream>>>(a,b,Ls,&lcnt[r],Us,&rcnt[r-1],&rcnt[r-1]);
    k_dil11   <<<EG1,NT,0,stream>>>(a,d2,cover,misb,Ls,&lcnt[r],Us,&rcnt[r-1],&rcnt[r-1],ep);
    k_dil21   <<<EG1,NT,0,stream>>>(a,d2,cover,Ls,&lcnt[r],&rcnt[r-1],ep);
    k_fincomp1<<<EG1,NT,0,stream>>>(a,b,cover,n,Ls,&lcnt[r],Ld,&lcnt[r+1],
                                    Us,&rcnt[r-1],Ud,&rcnt[r],&rcnt[r-1]);
  }

  // ---- cluster propagation (bitmask-filtered) ----
  k_cluster_init<<<NB,NT,0,stream>>>(misb,reach1b,a,b,n);
  k_chop1 <<<EG0,NT,0,stream>>>(b,misb,reach1b,row,col,E);
  k_chop2f<<<EG0,NT,0,stream>>>(a,b,reach1b,row,col,n,E);

  // ---- unique -> cluster ids ----
  k_mark <<<NB,NT,0,stream>>>(a,misb,present,scal,n);
  k_scan1<<<NBs,NT,0,stream>>>(present,n,bsum);
  k_scan2<<<1,NT,0,stream>>>(bsum,bscan,NBs,scal+1);
  k_scan3<<<NBs,NT,0,stream>>>(present,n,bscan,pref);
  k_assign<<<NB,NT,0,stream>>>(a,pref,cl,ccount,n);

  // ---- fill dense (c now known on device) ----
  k_fill_dense<<<2048,NT,0,stream>>>(dense,scal,CMsq);

  // ---- counting sort by cluster (scans bounded by CU_B >= c) ----
  k_scan1<<<NBc,NT,0,stream>>>(ccount,CU_B,bsum);
  k_scan2<<<1,NT,0,stream>>>(bsum,bscan,NBc,nullptr);
  k_scan3<<<NBc,NT,0,stream>>>(ccount,CU_B,bscan,pref);
  k_scatter_nodes<<<NB,NT,0,stream>>>(cl,pref,cursor,nodeList,n);

  // ---- x_pooled ----
  k_pool_x<<<1024,1024,0,stream>>>(x,nodeList,pref,ccount,scal,(float*)d_out,(long)out_size);

  // ---- pooled adjacency ----
  k_edge_pool<<<EG0,NT,0,stream>>>(row,col,eattr,cl,scal,dense,E,CMsq);
  k_cscan1<<<CB,NT,0,stream>>>(dense,scal,bsum,CMsq);
  k_scan2 <<<1,NT,0,stream>>>(bsum,bscan,CB,scal+2);
  k_cemit <<<CB,NT,0,stream>>>(dense,scal,bscan,(float*)d_out,(long)out_size,CMsq);
}

// Round 11
// 1823.059 us; speedup vs baseline: 1.1090x; 1.0604x over previous
//
#include <hip/hip_runtime.h>
#include <cmath>
#include <cstdint>

#define NT 256
#define EG0 1024          // grid for full-E passes
#define EG1 256           // grid for compacted passes
#define MAX_ROUND 16
#define KCOPY 4           // privatized dense copies (contention split)
#define SCAN_T 32
#define SCAN_IPB (NT*SCAN_T)
#define SENT 0x80000000u  // -0.0f sentinel: fadd identity, survives copy-sum

// ---------- helpers ----------

__device__ __forceinline__ int getbit(const unsigned int* bm, int v){
  return (bm[v>>5]>>(v&31))&1u;
}
__device__ __forceinline__ void setbit(unsigned int* bm, int v){
  unsigned int m = 1u<<(v&31);
  if(!(bm[v>>5]&m)) atomicOr(&bm[v>>5], m);   // rare-set, read-mostly usage only
}

__device__ __forceinline__ int block_append(int* cursor, bool pred, int* s_w){
  int wid  = threadIdx.x >> 6;
  int lane = threadIdx.x & 63;
  unsigned long long m = __ballot(pred);
  int cnt = __popcll(m);
  if(lane==0) s_w[wid]=cnt;
  __syncthreads();
  if(threadIdx.x==0){
    int t0=s_w[0], t1=s_w[1], t2=s_w[2], t3=s_w[3];
    int tot=t0+t1+t2+t3;
    int base = tot ? atomicAdd(cursor, tot) : 0;
    s_w[0]=base; s_w[1]=base+t0; s_w[2]=base+t0+t1; s_w[3]=base+t0+t1+t2;
  }
  __syncthreads();
  int pos = s_w[wid] + __popcll(m & ((1ull<<lane)-1ull));
  __syncthreads();
  return pos;
}

// ---------- init ----------

__global__ void k_init(int* a, int* b, int n){
  int v = blockIdx.x*NT + threadIdx.x;
  if(v<n){ a[v]=v; b[v]=v; }
}

// fill c*c cells of each of the K copies with SENT
__global__ void k_fill_dense(float* dcopies, const int* scal, long CMsq){
  long c = scal[0];
  long M = c*c; if(M>CMsq) M=CMsq;
  long stride = (long)gridDim.x*NT;
  for(long i = (long)blockIdx.x*NT + threadIdx.x; i<M; i+=stride){
    #pragma unroll
    for(int k=0;k<KCOPY;k++)
      ((unsigned int*)dcopies)[(long)k*CMsq + i] = SENT;
  }
}

// ---------- round 0 (full edge arrays) ----------

__global__ void k_hop0(int* b, const int* __restrict__ row,
                       const int* __restrict__ col, int E){
  int stride = gridDim.x*NT;
  for(int e = blockIdx.x*NT + threadIdx.x; e<E; e+=stride){
    int s = row[e];
    if(s < b[col[e]]) atomicMin(&b[col[e]], s);
  }
}

__global__ void k_hop0f(int* a, const int* b, const int* __restrict__ row,
                        const int* __restrict__ col, int n, int E){
  int stride = gridDim.x*NT;
  int total = n + E;
  for(int i = blockIdx.x*NT + threadIdx.x; i<total; i+=stride){
    if(i<n){
      if(b[i] < a[i]) atomicMin(&a[i], b[i]);
    } else {
      int e = i-n;
      int s = b[row[e]];
      if(s < a[col[e]]) atomicMin(&a[col[e]], s);
    }
  }
}

__global__ void k_dil0(const int* a, int* d2, int* cover, const int* __restrict__ row,
                       const int* __restrict__ col, int E, int ep){
  int stride = gridDim.x*NT;
  for(int e = blockIdx.x*NT + threadIdx.x; e<E; e+=stride){
    int r = row[e];
    if(a[r]==r){
      int cc = col[e];
      d2[r]=ep;  cover[r]=1;
      d2[cc]=ep; cover[cc]=1;
    }
  }
}

__global__ void k_dil20(const int* a, const int* d2, int* cover, const int* __restrict__ row,
                        const int* __restrict__ col, int E, int ep){
  int stride = gridDim.x*NT;
  for(int e = blockIdx.x*NT + threadIdx.x; e<E; e+=stride){
    int r = row[e];
    if((d2[r]==ep || a[r]==r) && !cover[col[e]]) cover[col[e]]=1;
  }
}

__global__ void k_fincomp0(int* a, int* b, unsigned int* misb, int* cover, int n,
                           const int* __restrict__ row, const int* __restrict__ col, int E,
                           int2* Ld, int* lcnt1, int* U1, int* rcnt0){
  __shared__ int s_w[4];
  long nth = (long)gridDim.x*NT;
  for(long base = (long)blockIdx.x*NT; base < n; base += nth){
    int v = (int)base + threadIdx.x;
    bool unc = false;
    if(v<n){
      int nw = (a[v]==v);
      if(nw){ setbit(misb,v); if(!cover[v]) cover[v]=1; }
      int cov = cover[v] | nw;
      int val = cov ? n : v;
      a[v]=val; b[v]=val;
      unc = !cov;
    }
    int pos = block_append(rcnt0, unc, s_w);
    if(unc) U1[pos]=v;
  }
  for(long base = (long)blockIdx.x*NT; base < E; base += nth){
    int e = (int)base + threadIdx.x;
    bool keep=false; int2 ed;
    if(e<E){
      ed = make_int2(row[e], col[e]);
      keep = (!cover[ed.x]) || (!cover[ed.y]);
    }
    int pos = block_append(lcnt1, keep, s_w);
    if(keep) Ld[pos]=ed;
  }
}

// ---------- rounds >=1 ----------

__global__ void k_hop1(int* b, const int* a, const int2* L, const int* pE,
                       const int* gate){
  if(*gate==0) return;
  int E = *pE;
  int stride = gridDim.x*NT;
  for(int e = blockIdx.x*NT + threadIdx.x; e<E; e+=stride){
    int2 ed = L[e];
    int s = a[ed.x];
    if(s < b[ed.y]) atomicMin(&b[ed.y], s);
  }
}

__global__ void k_hop1f(int* a, const int* b, const int2* L, const int* pE,
                        const int* U, const int* pU, const int* gate){
  if(*gate==0) return;
  int E = *pE, un = *pU;
  int total = un + E;
  int stride = gridDim.x*NT;
  for(int i = blockIdx.x*NT + threadIdx.x; i<total; i+=stride){
    if(i<un){
      int u = U[i];
      if(b[u] < a[u]) atomicMin(&a[u], b[u]);
    } else {
      int2 ed = L[i-un];
      int s = b[ed.x];
      if(s < a[ed.y]) atomicMin(&a[ed.y], s);
    }
  }
}

__global__ void k_dil11(const int* a, int* d2, int* cover, unsigned int* misb,
                        const int2* L, const int* pE, const int* U, const int* pU,
                        const int* gate, int ep){
  if(*gate==0) return;
  int E = *pE, un = *pU;
  int total = un + E;
  int stride = gridDim.x*NT;
  for(int i = blockIdx.x*NT + threadIdx.x; i<total; i+=stride){
    if(i<un){
      int u = U[i];
      if(a[u]==u){ setbit(misb,u); cover[u]=1; d2[u]=ep; }
    } else {
      int2 ed = L[i-un];
      if(a[ed.x]==ed.x){ d2[ed.x]=ep; cover[ed.x]=1; d2[ed.y]=ep; cover[ed.y]=1; }
    }
  }
}

__global__ void k_dil21(const int* a, const int* d2, int* cover, const int2* L,
                        const int* pE, const int* gate, int ep){
  if(*gate==0) return;
  int E = *pE;
  int stride = gridDim.x*NT;
  for(int e = blockIdx.x*NT + threadIdx.x; e<E; e+=stride){
    int2 ed = L[e];
    if((d2[ed.x]==ep || a[ed.x]==ed.x) && !cover[ed.y]) cover[ed.y]=1;
  }
}

__global__ void k_fincomp1(int* a, int* b, const int* cover, int n,
                           const int2* Ls, const int* pE, int2* Ld, int* lcntD,
                           const int* Us, const int* pU, int* Ud, int* rcntD,
                           const int* gate){
  if(*gate==0) return;
  __shared__ int s_w[4];
  int E = *pE, un = *pU;
  long nth = (long)gridDim.x*NT;
  for(long base = (long)blockIdx.x*NT; base < un; base += nth){
    int i = (int)base + threadIdx.x;
    bool unc=false; int u=0;
    if(i<un){ u = Us[i]; unc = !cover[u]; }
    int pos = block_append(rcntD, unc, s_w);
    if(unc) Ud[pos]=u;
  }
  for(long base = (long)blockIdx.x*NT; base < E; base += nth){
    int e = (int)base + threadIdx.x;
    bool keep=false; int2 ed;
    if(e<E){
      ed = Ls[e];
      int vx = cover[ed.x] ? n : ed.x;  a[ed.x]=vx; b[ed.x]=vx;
      int vy = cover[ed.y] ? n : ed.y;  a[ed.y]=vy; b[ed.y]=vy;
      keep = (!cover[ed.x]) || (!cover[ed.y]);
    }
    int pos = block_append(lcntD, keep, s_w);
    if(keep) Ld[pos]=ed;
  }
}

// ---------- cluster phase (bitmask-filtered) ----------

__global__ void k_cluster_init(const unsigned int* misb, unsigned int* reach1b,
                               int* a, int* b, int n){
  int v = blockIdx.x*NT + threadIdx.x;
  if(v<n){
    int m = getbit(misb,v);
    int val = m ? v : n;
    a[v]=val; b[v]=val;
    if(m) setbit(reach1b,v);
  }
}

__global__ void k_chop1(int* b, const unsigned int* misb, unsigned int* reach1b,
                        const int* __restrict__ row, const int* __restrict__ col, int E){
  int stride = gridDim.x*NT;
  for(int e = blockIdx.x*NT + threadIdx.x; e<E; e+=stride){
    int r = row[e];
    if(getbit(misb,r)){
      int cc = col[e];
      if(r < b[cc]) atomicMin(&b[cc], r);
      setbit(reach1b, cc);
    }
  }
}

__global__ void k_chop2f(int* a, const int* b, const unsigned int* reach1b,
                         const int* __restrict__ row, const int* __restrict__ col,
                         int n, int E){
  int stride = gridDim.x*NT;
  int total = n + E;
  for(int i = blockIdx.x*NT + threadIdx.x; i<total; i+=stride){
    if(i<n){
      if(b[i] < a[i]) atomicMin(&a[i], b[i]);
    } else {
      int e = i-n;
      int r = row[e];
      if(getbit(reach1b,r)){
        int s = b[r];
        if(s < n && s < a[col[e]]) atomicMin(&a[col[e]], s);
      }
    }
  }
}

__global__ void k_mark(const int* mr, const unsigned int* misb, int* present, int* cmis, int n){
  int v = blockIdx.x*NT + threadIdx.x;
  int m = 0;
  if(v<n){
    int r = mr[v];
    if(r<n && !present[r]) present[r]=1;
    m = getbit(misb,v);
  }
  __shared__ int sh[NT];
  sh[threadIdx.x]=m; __syncthreads();
  for(int off=NT/2; off>0; off>>=1){
    if(threadIdx.x<off) sh[threadIdx.x]+=sh[threadIdx.x+off];
    __syncthreads();
  }
  if(threadIdx.x==0 && sh[0]) atomicAdd(cmis, sh[0]);
}

// ---------- generic scan ----------

__global__ void k_scan1(const int* A, int M, int* bsum){
  int t = threadIdx.x;
  long base = (long)blockIdx.x*SCAN_IPB + (long)t*SCAN_T;
  int s = 0;
  #pragma unroll
  for(int j=0;j<SCAN_T;j++){ long i=base+j; if(i<M) s += A[i]; }
  __shared__ int sh[NT];
  sh[t]=s; __syncthreads();
  for(int off=NT/2; off>0; off>>=1){ if(t<off) sh[t]+=sh[t+off]; __syncthreads(); }
  if(t==0) bsum[blockIdx.x]=sh[0];
}

__global__ void k_scan2(const int* bsum, int* bscan, int B, int* totalOut){
  __shared__ int sh[NT];
  int t = threadIdx.x;
  int carry = 0;
  for(int base=0; base<B; base+=NT){
    int i = base+t;
    int v = (i<B) ? bsum[i] : 0;
    sh[t]=v; __syncthreads();
    for(int off=1; off<NT; off<<=1){
      int x=0; if(t>=off) x=sh[t-off];
      __syncthreads();
      sh[t]+=x; __syncthreads();
    }
    int incl = sh[t];
    if(i<B) bscan[i] = carry + incl - v;
    carry += sh[NT-1];
    __syncthreads();
  }
  if(t==0 && totalOut) *totalOut = carry;
}

__global__ void k_scan3(const int* A, int M, const int* bscan, int* pref){
  int t = threadIdx.x;
  long base = (long)blockIdx.x*SCAN_IPB + (long)t*SCAN_T;
  int s = 0;
  #pragma unroll
  for(int j=0;j<SCAN_T;j++){ long i=base+j; if(i<M) s += A[i]; }
  __shared__ int sh[NT];
  sh[t]=s; __syncthreads();
  for(int off=1; off<NT; off<<=1){
    int x=0; if(t>=off) x=sh[t-off];
    __syncthreads();
    sh[t]+=x; __syncthreads();
  }
  int run = bscan[blockIdx.x] + (sh[t]-s);
  for(int j=0;j<SCAN_T;j++){
    long i=base+j;
    if(i<M){ pref[i]=run; run += A[i]; }
  }
}

// ---------- clustering & pooling ----------

__global__ void k_assign(const int* mr, const int* pref, int* cl, int* ccount, int n){
  int v = blockIdx.x*NT + threadIdx.x;
  if(v<n){
    int r = mr[v];
    int cid = (r<n) ? pref[r] : 0;
    cl[v]=cid;
    atomicAdd(&ccount[cid],1);
  }
}

__global__ void k_scatter_nodes(const int* cl, const int* cstart, int* cursor, int* nodeList, int n){
  int v = blockIdx.x*NT + threadIdx.x;
  if(v<n){
    int cid = cl[v];
    int pos = cstart[cid] + atomicAdd(&cursor[cid],1);
    nodeList[pos]=v;
  }
}

// round-8 proven: one 256-thread block per cluster, ILP4
__global__ void k_pool_x(const float* __restrict__ x, const int* nodeList, const int* cstart,
                         const int* ccount, const int* scal, float* out, long out_size){
  int c = scal[0], U = scal[1];
  int t = threadIdx.x;
  for(int cid=blockIdx.x; cid<c; cid+=gridDim.x){
    float s0=0.f, s1=0.f, s2=0.f, s3=0.f;
    if(cid<U){
      int st = cstart[cid], cn = ccount[cid];
      int i=0;
      for(; i+3<cn; i+=4){
        int n0=nodeList[st+i], n1=nodeList[st+i+1], n2=nodeList[st+i+2], n3=nodeList[st+i+3];
        s0 += x[(size_t)n0*256 + t];
        s1 += x[(size_t)n1*256 + t];
        s2 += x[(size_t)n2*256 + t];
        s3 += x[(size_t)n3*256 + t];
      }
      for(; i<cn; i++) s0 += x[(size_t)nodeList[st+i]*256 + t];
      s0 += s1+s2+s3;
    }
    long idx = (long)cid*256 + t;
    if(idx < out_size) out[idx]=s0;
  }
}

// one fp32 atomic per edge into a privatized copy (blockIdx & 3)
__global__ void k_edge_pool(const int* __restrict__ row, const int* __restrict__ col,
                            const float* __restrict__ attr, const int* cl,
                            const int* scal, float* dcopies, int E, long CMsq){
  int c = scal[0];
  float* dc = dcopies + (long)(blockIdx.x & (KCOPY-1))*CMsq;
  int stride = gridDim.x*NT;
  for(int e = blockIdx.x*NT + threadIdx.x; e<E; e+=stride){
    long key = (long)cl[row[e]]*c + cl[col[e]];
    if(key < CMsq){
      unsafeAtomicAdd(&dc[key], attr[e]);
    }
  }
}

// dense[i] = sum of K copies (-0.0 is fadd identity; all-SENT stays SENT)
__global__ void k_reduce_dense(const float* __restrict__ dcopies, float* dense,
                               const int* scal, long CMsq){
  long c = scal[0];
  long M = c*c; if(M>CMsq) M=CMsq;
  long stride = (long)gridDim.x*NT;
  for(long i = (long)blockIdx.x*NT + threadIdx.x; i<M; i+=stride){
    float s = dcopies[i];
    #pragma unroll
    for(int k=1;k<KCOPY;k++) s += dcopies[(long)k*CMsq + i];
    dense[i]=s;
  }
}

__device__ __forceinline__ int cellp(const float* dense, long i){
  return __float_as_uint(dense[i]) != SENT;
}

__global__ void k_cscan1(const float* dense, const int* scal, int* bsum, long CMsq){
  int c = scal[0];
  long M = (long)c*c; if(M>CMsq) M=CMsq;
  int t = threadIdx.x;
  long base = (long)blockIdx.x*SCAN_IPB + (long)t*SCAN_T;
  int s = 0;
  if(base < M && c > 0){
    int r = (int)(base / c);
    int q = (int)(base - (long)r*c);
    for(int j=0;j<SCAN_T;j++){
      long i=base+j;
      if(i<M){
        if(cellp(dense,i) && r!=q) s++;
      }
      if(++q==c){ q=0; r++; }
    }
  }
  __shared__ int sh[NT];
  sh[t]=s; __syncthreads();
  for(int off=NT/2; off>0; off>>=1){ if(t<off) sh[t]+=sh[t+off]; __syncthreads(); }
  if(t==0) bsum[blockIdx.x]=sh[0];
}

__global__ void k_cemit(const float* dense, const int* scal,
                        const int* bscan, float* out, long out_size, long CMsq){
  int c = scal[0]; int P = scal[2];
  long M = (long)c*c; if(M>CMsq) M=CMsq;
  long xoff = (long)c*256;
  int t = threadIdx.x;
  long base = (long)blockIdx.x*SCAN_IPB + (long)t*SCAN_T;
  int s = 0;
  int r0=0,q0=0;
  if(base < M && c > 0){
    r0 = (int)(base / c);
    q0 = (int)(base - (long)r0*c);
    int r=r0, q=q0;
    for(int j=0;j<SCAN_T;j++){
      long i=base+j;
      if(i<M){
        if(cellp(dense,i) && r!=q) s++;
      }
      if(++q==c){ q=0; r++; }
    }
  }
  __shared__ int sh[NT];
  sh[t]=s; __syncthreads();
  for(int off=1; off<NT; off<<=1){
    int x=0; if(t>=off) x=sh[t-off];
    __syncthreads();
    sh[t]+=x; __syncthreads();
  }
  int run = bscan[blockIdx.x] + (sh[t]-s);
  if(base < M && c > 0){
    int r=r0, q=q0;
    for(int j=0;j<SCAN_T;j++){
      long i=base+j;
      if(i<M && cellp(dense,i) && r!=q){
        long o0 = xoff + run;
        long o1 = xoff + (long)P + run;
        long o2 = xoff + 2L*(long)P + run;
        if(o0<out_size) out[o0]=(float)r;
        if(o1<out_size) out[o1]=(float)q;
        if(o2<out_size) out[o2]=dense[i];
        run++;
      }
      if(++q==c){ q=0; r++; }
    }
  }
}

// ---------- host ----------

extern "C" void kernel_launch(void* const* d_in, const int* in_sizes, int n_in,
                              void* d_out, int out_size, void* d_ws, size_t ws_size,
                              hipStream_t stream){
  (void)n_in;
  const float* x     = (const float*)d_in[0];
  const int*   eidx  = (const int*)d_in[1];
  const float* eattr = (const float*)d_in[2];
  const int D = 256;
  int n = in_sizes[0]/D;
  int E = in_sizes[1]/2;
  const int* row = eidx;
  const int* col = eidx + E;
  int nwords = (n+31)>>5;
  int CU_B = out_size/256 + 1; if(CU_B > n) CU_B = n;   // host-known bound: c <= CU_B

  char* p = (char*)d_ws;
  auto alloc = [&](size_t bytes)->char*{ char* r=p; p += (bytes+255)&~(size_t)255; return r; };
  int2* LA   = (int2*)alloc((size_t)E*8);
  int2* LB   = (int2*)alloc((size_t)E*8);
  int* a     = (int*)alloc((size_t)n*4);
  int* b     = (int*)alloc((size_t)n*4);
  int* cl    = (int*)alloc((size_t)n*4);
  int* nodeList = (int*)alloc((size_t)n*4);
  int* pref  = (int*)alloc((size_t)n*4);
  int* U1    = (int*)alloc((size_t)n*4);
  int* U2    = (int*)alloc((size_t)n*4);
  int* bsum  = (int*)alloc(4096*4);
  int* bscan = (int*)alloc(4096*4);
  char* zstart = p;                         // zeroed each call
  int* cover   = (int*)alloc((size_t)n*4);
  int* d2      = (int*)alloc((size_t)n*4);
  unsigned int* misb    = (unsigned int*)alloc((size_t)nwords*4);
  unsigned int* reach1b = (unsigned int*)alloc((size_t)nwords*4);
  int* present = (int*)alloc((size_t)n*4);
  int* ccount  = (int*)alloc((size_t)n*4);
  int* cursor  = (int*)alloc((size_t)n*4);
  int* rcnt    = (int*)alloc((MAX_ROUND+2)*4);
  int* lcnt    = (int*)alloc((MAX_ROUND+2)*4);
  int* scal    = (int*)alloc(64);              // [0]=c, [1]=U, [2]=P
  size_t zbytes = (size_t)(p - zstart);

  size_t used   = (size_t)(p-(char*)d_ws);
  size_t remain = (ws_size > used+4096) ? ws_size-used-4096 : 0;
  size_t maxcells = remain/(4*(KCOPY+1));
  long CM = CU_B;
  while(CM>1 && (size_t)CM*CM > maxcells) CM--;   // safety cap (shouldn't trigger here)
  long CMsq = CM*CM;
  float* dcopies = (float*)alloc((size_t)KCOPY*CMsq*4);
  float* dense   = (float*)alloc((size_t)CMsq*4);

  hipMemsetAsync(zstart, 0, zbytes, stream);

  int NB  = (n+NT-1)/NT;
  int NBs = (n+SCAN_IPB-1)/SCAN_IPB;
  int NBc = (CU_B+SCAN_IPB-1)/SCAN_IPB;
  int CB  = (int)((CMsq+SCAN_IPB-1)/SCAN_IPB);
  if(CB>4096) CB=4096;

  // ---- round 0 (full graph) ----
  k_init    <<<NB,NT,0,stream>>>(a,b,n);
  k_hop0    <<<EG0,NT,0,stream>>>(b,row,col,E);
  k_hop0f   <<<EG0,NT,0,stream>>>(a,b,row,col,n,E);
  k_dil0    <<<EG0,NT,0,stream>>>(a,d2,cover,row,col,E,1);
  k_dil20   <<<EG0,NT,0,stream>>>(a,d2,cover,row,col,E,1);
  k_fincomp0<<<EG0,NT,0,stream>>>(a,b,misb,cover,n,row,col,E,LB,&lcnt[1],U1,&rcnt[0]);

  // ---- rounds 1..MAX_ROUND-1 (compacted, gated) ----
  for(int r=1; r<MAX_ROUND; ++r){
    int2* Ls = (r&1) ? LB : LA;
    int2* Ld = (r&1) ? LA : LB;
    int*  Us = (r&1) ? U1 : U2;
    int*  Ud = (r&1) ? U2 : U1;
    int ep = r+1;
    k_hop1    <<<EG1,NT,0,stream>>>(b,a,Ls,&lcnt[r],&rcnt[r-1]);
    k_hop1f   <<<EG1,NT,0,stream>>>(a,b,Ls,&lcnt[r],Us,&rcnt[r-1],&rcnt[r-1]);
    k_dil11   <<<EG1,NT,0,stream>>>(a,d2,cover,misb,Ls,&lcnt[r],Us,&rcnt[r-1],&rcnt[r-1],ep);
    k_dil21   <<<EG1,NT,0,stream>>>(a,d2,cover,Ls,&lcnt[r],&rcnt[r-1],ep);
    k_fincomp1<<<EG1,NT,0,stream>>>(a,b,cover,n,Ls,&lcnt[r],Ld,&lcnt[r+1],
                                    Us,&rcnt[r-1],Ud,&rcnt[r],&rcnt[r-1]);
  }

  // ---- cluster propagation (bitmask-filtered) ----
  k_cluster_init<<<NB,NT,0,stream>>>(misb,reach1b,a,b,n);
  k_chop1 <<<EG0,NT,0,stream>>>(b,misb,reach1b,row,col,E);
  k_chop2f<<<EG0,NT,0,stream>>>(a,b,reach1b,row,col,n,E);

  // ---- unique -> cluster ids ----
  k_mark <<<NB,NT,0,stream>>>(a,misb,present,scal,n);
  k_scan1<<<NBs,NT,0,stream>>>(present,n,bsum);
  k_scan2<<<1,NT,0,stream>>>(bsum,bscan,NBs,scal+1);
  k_scan3<<<NBs,NT,0,stream>>>(present,n,bscan,pref);
  k_assign<<<NB,NT,0,stream>>>(a,pref,cl,ccount,n);

  // ---- fill privatized dense copies (c now known on device) ----
  k_fill_dense<<<2048,NT,0,stream>>>(dcopies,scal,CMsq);

  // ---- counting sort by cluster (scans bounded by CU_B >= c) ----
  k_scan1<<<NBc,NT,0,stream>>>(ccount,CU_B,bsum);
  k_scan2<<<1,NT,0,stream>>>(bsum,bscan,NBc,nullptr);
  k_scan3<<<NBc,NT,0,stream>>>(ccount,CU_B,bscan,pref);
  k_scatter_nodes<<<NB,NT,0,stream>>>(cl,pref,cursor,nodeList,n);

  // ---- x_pooled ----
  k_pool_x<<<1024,NT,0,stream>>>(x,nodeList,pref,ccount,scal,(float*)d_out,(long)out_size);

  // ---- pooled adjacency ----
  k_edge_pool<<<EG0,NT,0,stream>>>(row,col,eattr,cl,scal,dcopies,E,CMsq);
  k_reduce_dense<<<1024,NT,0,stream>>>(dcopies,dense,scal,CMsq);
  k_cscan1<<<CB,NT,0,stream>>>(dense,scal,bsum,CMsq);
  k_scan2 <<<1,NT,0,stream>>>(bsum,bscan,CB,scal+2);
  k_cemit <<<CB,NT,0,stream>>>(dense,scal,bscan,(float*)d_out,(long)out_size,CMsq);
}

// Round 12
// 1779.838 us; speedup vs baseline: 1.1359x; 1.0243x over previous
//
#include <hip/hip_runtime.h>
#include <cmath>
#include <cstdint>

#define NT 256
#define EG0 1024          // grid for full-E passes
#define EG1 256           // grid for compacted passes
#define MAX_ROUND 16
#define KCOPY 4           // privatized dense copies (contention split)
#define SCAN_T 32
#define SCAN_IPB (NT*SCAN_T)
#define SENT 0x80000000u  // -0.0f sentinel: fadd identity, survives copy-sum

// ---------- helpers ----------

__device__ __forceinline__ int getbit(const unsigned int* bm, int v){
  return (bm[v>>5]>>(v&31))&1u;
}
__device__ __forceinline__ void setbit(unsigned int* bm, int v){
  unsigned int m = 1u<<(v&31);
  if(!(bm[v>>5]&m)) atomicOr(&bm[v>>5], m);
}

__device__ __forceinline__ int block_append(int* cursor, bool pred, int* s_w){
  int wid  = threadIdx.x >> 6;
  int lane = threadIdx.x & 63;
  unsigned long long m = __ballot(pred);
  int cnt = __popcll(m);
  if(lane==0) s_w[wid]=cnt;
  __syncthreads();
  if(threadIdx.x==0){
    int t0=s_w[0], t1=s_w[1], t2=s_w[2], t3=s_w[3];
    int tot=t0+t1+t2+t3;
    int base = tot ? atomicAdd(cursor, tot) : 0;
    s_w[0]=base; s_w[1]=base+t0; s_w[2]=base+t0+t1; s_w[3]=base+t0+t1+t2;
  }
  __syncthreads();
  int pos = s_w[wid] + __popcll(m & ((1ull<<lane)-1ull));
  __syncthreads();
  return pos;
}

// ---------- init ----------

__global__ void k_init(int* a, int* b, int n){
  int v = blockIdx.x*NT + threadIdx.x;
  if(v<n){ a[v]=v; b[v]=v; }
}

__global__ void k_fill_dense(float* dcopies, const int* scal, long CMsq){
  long c = scal[0];
  long M = c*c; if(M>CMsq) M=CMsq;
  long stride = (long)gridDim.x*NT;
  for(long i = (long)blockIdx.x*NT + threadIdx.x; i<M; i+=stride){
    #pragma unroll
    for(int k=0;k<KCOPY;k++)
      ((unsigned int*)dcopies)[(long)k*CMsq + i] = SENT;
  }
}

// ---------- round 0 (full edge arrays, ILP4) ----------

__global__ void k_hop0(int* b, const int* __restrict__ row,
                       const int* __restrict__ col, int E){
  int stride = gridDim.x*NT*4;
  for(int base = (blockIdx.x*NT + threadIdx.x)*4; base<E; base+=stride){
    int r[4], c[4], bv[4];
    #pragma unroll
    for(int j=0;j<4;j++) if(base+j<E){ r[j]=row[base+j]; c[j]=col[base+j]; }
    #pragma unroll
    for(int j=0;j<4;j++) if(base+j<E) bv[j]=b[c[j]];
    #pragma unroll
    for(int j=0;j<4;j++) if(base+j<E && r[j]<bv[j]) atomicMin(&b[c[j]], r[j]);
  }
}

// node self-fold + edge hop2 (both atomicMin into a: commutative)
__global__ void k_hop0f(int* a, const int* b, const int* __restrict__ row,
                        const int* __restrict__ col, int n, int E){
  int stride = gridDim.x*NT;
  for(int i = blockIdx.x*NT + threadIdx.x; i<n; i+=stride){
    if(b[i] < a[i]) atomicMin(&a[i], b[i]);
  }
  int stride4 = gridDim.x*NT*4;
  for(int base = (blockIdx.x*NT + threadIdx.x)*4; base<E; base+=stride4){
    int r[4], c[4], s[4], av[4];
    #pragma unroll
    for(int j=0;j<4;j++) if(base+j<E){ r[j]=row[base+j]; c[j]=col[base+j]; }
    #pragma unroll
    for(int j=0;j<4;j++) if(base+j<E) s[j]=b[r[j]];
    #pragma unroll
    for(int j=0;j<4;j++) if(base+j<E) av[j]=a[c[j]];
    #pragma unroll
    for(int j=0;j<4;j++) if(base+j<E && s[j]<av[j]) atomicMin(&a[c[j]], s[j]);
  }
}

__global__ void k_dil0(const int* a, int* d2, int* cover, const int* __restrict__ row,
                       const int* __restrict__ col, int E, int ep){
  int stride = gridDim.x*NT*4;
  for(int base = (blockIdx.x*NT + threadIdx.x)*4; base<E; base+=stride){
    int r[4], av[4];
    #pragma unroll
    for(int j=0;j<4;j++) if(base+j<E) r[j]=row[base+j];
    #pragma unroll
    for(int j=0;j<4;j++) if(base+j<E) av[j]=a[r[j]];
    #pragma unroll
    for(int j=0;j<4;j++) if(base+j<E && av[j]==r[j]){
      int cc = col[base+j];
      d2[r[j]]=ep;  cover[r[j]]=1;
      d2[cc]=ep; cover[cc]=1;
    }
  }
}

__global__ void k_dil20(const int* a, const int* d2, int* cover, const int* __restrict__ row,
                        const int* __restrict__ col, int E, int ep){
  int stride = gridDim.x*NT*4;
  for(int base = (blockIdx.x*NT + threadIdx.x)*4; base<E; base+=stride){
    int r[4], dv[4];
    #pragma unroll
    for(int j=0;j<4;j++) if(base+j<E) r[j]=row[base+j];
    #pragma unroll
    for(int j=0;j<4;j++) if(base+j<E) dv[j]=d2[r[j]];
    #pragma unroll
    for(int j=0;j<4;j++) if(base+j<E && (dv[j]==ep || a[r[j]]==r[j])){
      int cc = col[base+j];
      if(!cover[cc]) cover[cc]=1;
    }
  }
}

__global__ void k_fincomp0(int* a, int* b, unsigned int* misb, int* cover, int n,
                           const int* __restrict__ row, const int* __restrict__ col, int E,
                           int2* Ld, int* lcnt1, int* U1, int* rcnt0){
  __shared__ int s_w[4];
  long nth = (long)gridDim.x*NT;
  for(long base = (long)blockIdx.x*NT; base < n; base += nth){
    int v = (int)base + threadIdx.x;
    bool unc = false;
    if(v<n){
      int nw = (a[v]==v);
      if(nw){ setbit(misb,v); if(!cover[v]) cover[v]=1; }
      int cov = cover[v] | nw;
      int val = cov ? n : v;
      a[v]=val; b[v]=val;
      unc = !cov;
    }
    int pos = block_append(rcnt0, unc, s_w);
    if(unc) U1[pos]=v;
  }
  // edge compaction: prefetch 8 gathers, then 4 ordered appends
  long nth4 = nth*4;
  for(long base = (long)blockIdx.x*NT*4; base < E; base += nth4){
    int e0 = (int)base + threadIdx.x*4;
    int2 ed[4]; int cx[4], cy[4]; bool keep[4];
    #pragma unroll
    for(int j=0;j<4;j++) if(e0+j<E) ed[j]=make_int2(row[e0+j], col[e0+j]);
    #pragma unroll
    for(int j=0;j<4;j++) if(e0+j<E){ cx[j]=cover[ed[j].x]; cy[j]=cover[ed[j].y]; }
    #pragma unroll
    for(int j=0;j<4;j++) keep[j] = (e0+j<E) && ((!cx[j]) || (!cy[j]));
    #pragma unroll
    for(int j=0;j<4;j++){
      int pos = block_append(lcnt1, keep[j], s_w);
      if(keep[j]) Ld[pos]=ed[j];
    }
  }
}

// ---------- rounds >=1 (compacted, gated, ILP4) ----------

__global__ void k_hop1(int* b, const int* a, const int2* L, const int* pE,
                       const int* gate){
  if(*gate==0) return;
  int E = *pE;
  int stride = gridDim.x*NT*4;
  for(int base = (blockIdx.x*NT + threadIdx.x)*4; base<E; base+=stride){
    int2 ed[4]; int s[4], bv[4];
    #pragma unroll
    for(int j=0;j<4;j++) if(base+j<E) ed[j]=L[base+j];
    #pragma unroll
    for(int j=0;j<4;j++) if(base+j<E) s[j]=a[ed[j].x];
    #pragma unroll
    for(int j=0;j<4;j++) if(base+j<E) bv[j]=b[ed[j].y];
    #pragma unroll
    for(int j=0;j<4;j++) if(base+j<E && s[j]<bv[j]) atomicMin(&b[ed[j].y], s[j]);
  }
}

__global__ void k_hop1f(int* a, const int* b, const int2* L, const int* pE,
                        const int* U, const int* pU, const int* gate){
  if(*gate==0) return;
  int E = *pE, un = *pU;
  int stride = gridDim.x*NT;
  for(int i = blockIdx.x*NT + threadIdx.x; i<un; i+=stride){
    int u = U[i];
    if(b[u] < a[u]) atomicMin(&a[u], b[u]);
  }
  int stride4 = gridDim.x*NT*4;
  for(int base = (blockIdx.x*NT + threadIdx.x)*4; base<E; base+=stride4){
    int2 ed[4]; int s[4], av[4];
    #pragma unroll
    for(int j=0;j<4;j++) if(base+j<E) ed[j]=L[base+j];
    #pragma unroll
    for(int j=0;j<4;j++) if(base+j<E) s[j]=b[ed[j].x];
    #pragma unroll
    for(int j=0;j<4;j++) if(base+j<E) av[j]=a[ed[j].y];
    #pragma unroll
    for(int j=0;j<4;j++) if(base+j<E && s[j]<av[j]) atomicMin(&a[ed[j].y], s[j]);
  }
}

__global__ void k_dil11(const int* a, int* d2, int* cover, unsigned int* misb,
                        const int2* L, const int* pE, const int* U, const int* pU,
                        const int* gate, int ep){
  if(*gate==0) return;
  int E = *pE, un = *pU;
  int stride = gridDim.x*NT;
  for(int i = blockIdx.x*NT + threadIdx.x; i<un; i+=stride){
    int u = U[i];
    if(a[u]==u){ setbit(misb,u); cover[u]=1; d2[u]=ep; }
  }
  int stride4 = gridDim.x*NT*4;
  for(int base = (blockIdx.x*NT + threadIdx.x)*4; base<E; base+=stride4){
    int2 ed[4]; int av[4];
    #pragma unroll
    for(int j=0;j<4;j++) if(base+j<E) ed[j]=L[base+j];
    #pragma unroll
    for(int j=0;j<4;j++) if(base+j<E) av[j]=a[ed[j].x];
    #pragma unroll
    for(int j=0;j<4;j++) if(base+j<E && av[j]==ed[j].x){
      d2[ed[j].x]=ep; cover[ed[j].x]=1;
      d2[ed[j].y]=ep; cover[ed[j].y]=1;
    }
  }
}

__global__ void k_dil21(const int* a, const int* d2, int* cover, const int2* L,
                        const int* pE, const int* gate, int ep){
  if(*gate==0) return;
  int E = *pE;
  int stride = gridDim.x*NT*4;
  for(int base = (blockIdx.x*NT + threadIdx.x)*4; base<E; base+=stride){
    int2 ed[4]; int dv[4];
    #pragma unroll
    for(int j=0;j<4;j++) if(base+j<E) ed[j]=L[base+j];
    #pragma unroll
    for(int j=0;j<4;j++) if(base+j<E) dv[j]=d2[ed[j].x];
    #pragma unroll
    for(int j=0;j<4;j++) if(base+j<E && (dv[j]==ep || a[ed[j].x]==ed[j].x)){
      if(!cover[ed[j].y]) cover[ed[j].y]=1;
    }
  }
}

__global__ void k_fincomp1(int* a, int* b, const int* cover, int n,
                           const int2* Ls, const int* pE, int2* Ld, int* lcntD,
                           const int* Us, const int* pU, int* Ud, int* rcntD,
                           const int* gate){
  if(*gate==0) return;
  __shared__ int s_w[4];
  int E = *pE, un = *pU;
  long nth = (long)gridDim.x*NT;
  for(long base = (long)blockIdx.x*NT; base < un; base += nth){
    int i = (int)base + threadIdx.x;
    bool unc=false; int u=0;
    if(i<un){ u = Us[i]; unc = !cover[u]; }
    int pos = block_append(rcntD, unc, s_w);
    if(unc) Ud[pos]=u;
  }
  long nth4 = nth*4;
  for(long base = (long)blockIdx.x*NT*4; base < E; base += nth4){
    int e0 = (int)base + threadIdx.x*4;
    int2 ed[4]; int cx[4], cy[4]; bool keep[4];
    #pragma unroll
    for(int j=0;j<4;j++) if(e0+j<E) ed[j]=Ls[e0+j];
    #pragma unroll
    for(int j=0;j<4;j++) if(e0+j<E){ cx[j]=cover[ed[j].x]; cy[j]=cover[ed[j].y]; }
    #pragma unroll
    for(int j=0;j<4;j++){
      if(e0+j<E){
        int vx = cx[j] ? n : ed[j].x;  a[ed[j].x]=vx; b[ed[j].x]=vx;
        int vy = cy[j] ? n : ed[j].y;  a[ed[j].y]=vy; b[ed[j].y]=vy;
      }
      bool k = (e0+j<E) && ((!cx[j]) || (!cy[j]));
      int pos = block_append(lcntD, k, s_w);
      if(k) Ld[pos]=ed[j];
    }
  }
}

// ---------- cluster phase (bitmask-filtered, ILP4) ----------

__global__ void k_cluster_init(const unsigned int* misb, unsigned int* reach1b,
                               int* a, int* b, int n){
  int v = blockIdx.x*NT + threadIdx.x;
  if(v<n){
    int m = getbit(misb,v);
    int val = m ? v : n;
    a[v]=val; b[v]=val;
    if(m) setbit(reach1b,v);
  }
}

__global__ void k_chop1(int* b, const unsigned int* misb, unsigned int* reach1b,
                        const int* __restrict__ row, const int* __restrict__ col, int E){
  int stride = gridDim.x*NT*4;
  for(int base = (blockIdx.x*NT + threadIdx.x)*4; base<E; base+=stride){
    int r[4], mb[4];
    #pragma unroll
    for(int j=0;j<4;j++) if(base+j<E) r[j]=row[base+j];
    #pragma unroll
    for(int j=0;j<4;j++) if(base+j<E) mb[j]=getbit(misb,r[j]);
    #pragma unroll
    for(int j=0;j<4;j++) if(base+j<E && mb[j]){
      int cc = col[base+j];
      if(r[j] < b[cc]) atomicMin(&b[cc], r[j]);
      setbit(reach1b, cc);
    }
  }
}

__global__ void k_chop2f(int* a, const int* b, const unsigned int* reach1b,
                         const int* __restrict__ row, const int* __restrict__ col,
                         int n, int E){
  int stride = gridDim.x*NT;
  for(int i = blockIdx.x*NT + threadIdx.x; i<n; i+=stride){
    if(b[i] < a[i]) atomicMin(&a[i], b[i]);
  }
  int stride4 = gridDim.x*NT*4;
  for(int base = (blockIdx.x*NT + threadIdx.x)*4; base<E; base+=stride4){
    int r[4], rb[4];
    #pragma unroll
    for(int j=0;j<4;j++) if(base+j<E) r[j]=row[base+j];
    #pragma unroll
    for(int j=0;j<4;j++) if(base+j<E) rb[j]=getbit(reach1b,r[j]);
    #pragma unroll
    for(int j=0;j<4;j++) if(base+j<E && rb[j]){
      int s = b[r[j]];
      if(s < n){
        int cc = col[base+j];
        if(s < a[cc]) atomicMin(&a[cc], s);
      }
    }
  }
}

__global__ void k_mark(const int* mr, const unsigned int* misb, int* present, int* cmis, int n){
  int v = blockIdx.x*NT + threadIdx.x;
  int m = 0;
  if(v<n){
    int r = mr[v];
    if(r<n && !present[r]) present[r]=1;
    m = getbit(misb,v);
  }
  __shared__ int sh[NT];
  sh[threadIdx.x]=m; __syncthreads();
  for(int off=NT/2; off>0; off>>=1){
    if(threadIdx.x<off) sh[threadIdx.x]+=sh[threadIdx.x+off];
    __syncthreads();
  }
  if(threadIdx.x==0 && sh[0]) atomicAdd(cmis, sh[0]);
}

// ---------- generic scan ----------

__global__ void k_scan1(const int* A, int M, int* bsum){
  int t = threadIdx.x;
  long base = (long)blockIdx.x*SCAN_IPB + (long)t*SCAN_T;
  int s = 0;
  #pragma unroll
  for(int j=0;j<SCAN_T;j++){ long i=base+j; if(i<M) s += A[i]; }
  __shared__ int sh[NT];
  sh[t]=s; __syncthreads();
  for(int off=NT/2; off>0; off>>=1){ if(t<off) sh[t]+=sh[t+off]; __syncthreads(); }
  if(t==0) bsum[blockIdx.x]=sh[0];
}

__global__ void k_scan2(const int* bsum, int* bscan, int B, int* totalOut){
  __shared__ int sh[NT];
  int t = threadIdx.x;
  int carry = 0;
  for(int base=0; base<B; base+=NT){
    int i = base+t;
    int v = (i<B) ? bsum[i] : 0;
    sh[t]=v; __syncthreads();
    for(int off=1; off<NT; off<<=1){
      int x=0; if(t>=off) x=sh[t-off];
      __syncthreads();
      sh[t]+=x; __syncthreads();
    }
    int incl = sh[t];
    if(i<B) bscan[i] = carry + incl - v;
    carry += sh[NT-1];
    __syncthreads();
  }
  if(t==0 && totalOut) *totalOut = carry;
}

__global__ void k_scan3(const int* A, int M, const int* bscan, int* pref){
  int t = threadIdx.x;
  long base = (long)blockIdx.x*SCAN_IPB + (long)t*SCAN_T;
  int s = 0;
  #pragma unroll
  for(int j=0;j<SCAN_T;j++){ long i=base+j; if(i<M) s += A[i]; }
  __shared__ int sh[NT];
  sh[t]=s; __syncthreads();
  for(int off=1; off<NT; off<<=1){
    int x=0; if(t>=off) x=sh[t-off];
    __syncthreads();
    sh[t]+=x; __syncthreads();
  }
  int run = bscan[blockIdx.x] + (sh[t]-s);
  for(int j=0;j<SCAN_T;j++){
    long i=base+j;
    if(i<M){ pref[i]=run; run += A[i]; }
  }
}

// ---------- clustering & pooling ----------

__global__ void k_assign(const int* mr, const int* pref, int* cl, int* ccount, int n){
  int v = blockIdx.x*NT + threadIdx.x;
  if(v<n){
    int r = mr[v];
    int cid = (r<n) ? pref[r] : 0;
    cl[v]=cid;
    atomicAdd(&ccount[cid],1);
  }
}

__global__ void k_scatter_nodes(const int* cl, const int* cstart, int* cursor, int* nodeList, int n){
  int v = blockIdx.x*NT + threadIdx.x;
  if(v<n){
    int cid = cl[v];
    int pos = cstart[cid] + atomicAdd(&cursor[cid],1);
    nodeList[pos]=v;
  }
}

// one 256-thread block per cluster, node-ILP8
__global__ void k_pool_x(const float* __restrict__ x, const int* nodeList, const int* cstart,
                         const int* ccount, const int* scal, float* out, long out_size){
  int c = scal[0], U = scal[1];
  int t = threadIdx.x;
  for(int cid=blockIdx.x; cid<c; cid+=gridDim.x){
    float s0=0.f,s1=0.f,s2=0.f,s3=0.f,s4=0.f,s5=0.f,s6=0.f,s7=0.f;
    if(cid<U){
      int st = cstart[cid], cn = ccount[cid];
      int i=0;
      for(; i+7<cn; i+=8){
        int n0=nodeList[st+i],   n1=nodeList[st+i+1], n2=nodeList[st+i+2], n3=nodeList[st+i+3];
        int n4=nodeList[st+i+4], n5=nodeList[st+i+5], n6=nodeList[st+i+6], n7=nodeList[st+i+7];
        s0 += x[(size_t)n0*256 + t]; s1 += x[(size_t)n1*256 + t];
        s2 += x[(size_t)n2*256 + t]; s3 += x[(size_t)n3*256 + t];
        s4 += x[(size_t)n4*256 + t]; s5 += x[(size_t)n5*256 + t];
        s6 += x[(size_t)n6*256 + t]; s7 += x[(size_t)n7*256 + t];
      }
      for(; i<cn; i++) s0 += x[(size_t)nodeList[st+i]*256 + t];
      s0 += s1+s2+s3+s4+s5+s6+s7;
    }
    long idx = (long)cid*256 + t;
    if(idx < out_size) out[idx]=s0;
  }
}

// one fp32 atomic per edge into privatized copy; ILP4 on cl gathers
__global__ void k_edge_pool(const int* __restrict__ row, const int* __restrict__ col,
                            const float* __restrict__ attr, const int* cl,
                            const int* scal, float* dcopies, int E, long CMsq){
  int c = scal[0];
  float* dc = dcopies + (long)(blockIdx.x & (KCOPY-1))*CMsq;
  int stride = gridDim.x*NT*4;
  for(int base = (blockIdx.x*NT + threadIdx.x)*4; base<E; base+=stride){
    int cr[4], cc[4]; float av[4];
    #pragma unroll
    for(int j=0;j<4;j++) if(base+j<E){ cr[j]=cl[row[base+j]]; }
    #pragma unroll
    for(int j=0;j<4;j++) if(base+j<E){ cc[j]=cl[col[base+j]]; av[j]=attr[base+j]; }
    #pragma unroll
    for(int j=0;j<4;j++) if(base+j<E){
      long key = (long)cr[j]*c + cc[j];
      if(key < CMsq) unsafeAtomicAdd(&dc[key], av[j]);
    }
  }
}

__global__ void k_reduce_dense(const float* __restrict__ dcopies, float* dense,
                               const int* scal, long CMsq){
  long c = scal[0];
  long M = c*c; if(M>CMsq) M=CMsq;
  long stride = (long)gridDim.x*NT;
  for(long i = (long)blockIdx.x*NT + threadIdx.x; i<M; i+=stride){
    float s = dcopies[i];
    #pragma unroll
    for(int k=1;k<KCOPY;k++) s += dcopies[(long)k*CMsq + i];
    dense[i]=s;
  }
}

__device__ __forceinline__ int cellp(const float* dense, long i){
  return __float_as_uint(dense[i]) != SENT;
}

__global__ void k_cscan1(const float* dense, const int* scal, int* bsum, long CMsq){
  int c = scal[0];
  long M = (long)c*c; if(M>CMsq) M=CMsq;
  int t = threadIdx.x;
  long base = (long)blockIdx.x*SCAN_IPB + (long)t*SCAN_T;
  int s = 0;
  if(base < M && c > 0){
    int r = (int)(base / c);
    int q = (int)(base - (long)r*c);
    for(int j=0;j<SCAN_T;j++){
      long i=base+j;
      if(i<M){
        if(cellp(dense,i) && r!=q) s++;
      }
      if(++q==c){ q=0; r++; }
    }
  }
  __shared__ int sh[NT];
  sh[t]=s; __syncthreads();
  for(int off=NT/2; off>0; off>>=1){ if(t<off) sh[t]+=sh[t+off]; __syncthreads(); }
  if(t==0) bsum[blockIdx.x]=sh[0];
}

__global__ void k_cemit(const float* dense, const int* scal,
                        const int* bscan, float* out, long out_size, long CMsq){
  int c = scal[0]; int P = scal[2];
  long M = (long)c*c; if(M>CMsq) M=CMsq;
  long xoff = (long)c*256;
  int t = threadIdx.x;
  long base = (long)blockIdx.x*SCAN_IPB + (long)t*SCAN_T;
  int s = 0;
  int r0=0,q0=0;
  if(base < M && c > 0){
    r0 = (int)(base / c);
    q0 = (int)(base - (long)r0*c);
    int r=r0, q=q0;
    for(int j=0;j<SCAN_T;j++){
      long i=base+j;
      if(i<M){
        if(cellp(dense,i) && r!=q) s++;
      }
      if(++q==c){ q=0; r++; }
    }
  }
  __shared__ int sh[NT];
  sh[t]=s; __syncthreads();
  for(int off=1; off<NT; off<<=1){
    int x=0; if(t>=off) x=sh[t-off];
    __syncthreads();
    sh[t]+=x; __syncthreads();
  }
  int run = bscan[blockIdx.x] + (sh[t]-s);
  if(base < M && c > 0){
    int r=r0, q=q0;
    for(int j=0;j<SCAN_T;j++){
      long i=base+j;
      if(i<M && cellp(dense,i) && r!=q){
        long o0 = xoff + run;
        long o1 = xoff + (long)P + run;
        long o2 = xoff + 2L*(long)P + run;
        if(o0<out_size) out[o0]=(float)r;
        if(o1<out_size) out[o1]=(float)q;
        if(o2<out_size) out[o2]=dense[i];
        run++;
      }
      if(++q==c){ q=0; r++; }
    }
  }
}

// ---------- host ----------

extern "C" void kernel_launch(void* const* d_in, const int* in_sizes, int n_in,
                              void* d_out, int out_size, void* d_ws, size_t ws_size,
                              hipStream_t stream){
  (void)n_in;
  const float* x     = (const float*)d_in[0];
  const int*   eidx  = (const int*)d_in[1];
  const float* eattr = (const float*)d_in[2];
  const int D = 256;
  int n = in_sizes[0]/D;
  int E = in_sizes[1]/2;
  const int* row = eidx;
  const int* col = eidx + E;
  int nwords = (n+31)>>5;
  int CU_B = out_size/256 + 1; if(CU_B > n) CU_B = n;

  char* p = (char*)d_ws;
  auto alloc = [&](size_t bytes)->char*{ char* r=p; p += (bytes+255)&~(size_t)255; return r; };
  int2* LA   = (int2*)alloc((size_t)E*8);
  int2* LB   = (int2*)alloc((size_t)E*8);
  int* a     = (int*)alloc((size_t)n*4);
  int* b     = (int*)alloc((size_t)n*4);
  int* cl    = (int*)alloc((size_t)n*4);
  int* nodeList = (int*)alloc((size_t)n*4);
  int* pref  = (int*)alloc((size_t)n*4);
  int* U1    = (int*)alloc((size_t)n*4);
  int* U2    = (int*)alloc((size_t)n*4);
  int* bsum  = (int*)alloc(4096*4);
  int* bscan = (int*)alloc(4096*4);
  char* zstart = p;                         // zeroed each call
  int* cover   = (int*)alloc((size_t)n*4);
  int* d2      = (int*)alloc((size_t)n*4);
  unsigned int* misb    = (unsigned int*)alloc((size_t)nwords*4);
  unsigned int* reach1b = (unsigned int*)alloc((size_t)nwords*4);
  int* present = (int*)alloc((size_t)n*4);
  int* ccount  = (int*)alloc((size_t)n*4);
  int* cursor  = (int*)alloc((size_t)n*4);
  int* rcnt    = (int*)alloc((MAX_ROUND+2)*4);
  int* lcnt    = (int*)alloc((MAX_ROUND+2)*4);
  int* scal    = (int*)alloc(64);              // [0]=c, [1]=U, [2]=P
  size_t zbytes = (size_t)(p - zstart);

  size_t used   = (size_t)(p-(char*)d_ws);
  size_t remain = (ws_size > used+4096) ? ws_size-used-4096 : 0;
  size_t maxcells = remain/(4*(KCOPY+1));
  long CM = CU_B;
  while(CM>1 && (size_t)CM*CM > maxcells) CM--;
  long CMsq = CM*CM;
  float* dcopies = (float*)alloc((size_t)KCOPY*CMsq*4);
  float* dense   = (float*)alloc((size_t)CMsq*4);

  hipMemsetAsync(zstart, 0, zbytes, stream);

  int NB  = (n+NT-1)/NT;
  int NBs = (n+SCAN_IPB-1)/SCAN_IPB;
  int NBc = (CU_B+SCAN_IPB-1)/SCAN_IPB;
  int CB  = (int)((CMsq+SCAN_IPB-1)/SCAN_IPB);
  if(CB>4096) CB=4096;

  // ---- round 0 (full graph) ----
  k_init    <<<NB,NT,0,stream>>>(a,b,n);
  k_hop0    <<<EG0,NT,0,stream>>>(b,row,col,E);
  k_hop0f   <<<EG0,NT,0,stream>>>(a,b,row,col,n,E);
  k_dil0    <<<EG0,NT,0,stream>>>(a,d2,cover,row,col,E,1);
  k_dil20   <<<EG0,NT,0,stream>>>(a,d2,cover,row,col,E,1);
  k_fincomp0<<<EG0,NT,0,stream>>>(a,b,misb,cover,n,row,col,E,LB,&lcnt[1],U1,&rcnt[0]);

  // ---- rounds 1..MAX_ROUND-1 (compacted, gated) ----
  for(int r=1; r<MAX_ROUND; ++r){
    int2* Ls = (r&1) ? LB : LA;
    int2* Ld = (r&1) ? LA : LB;
    int*  Us = (r&1) ? U1 : U2;
    int*  Ud = (r&1) ? U2 : U1;
    int ep = r+1;
    k_hop1    <<<EG1,NT,0,stream>>>(b,a,Ls,&lcnt[r],&rcnt[r-1]);
    k_hop1f   <<<EG1,NT,0,stream>>>(a,b,Ls,&lcnt[r],Us,&rcnt[r-1],&rcnt[r-1]);
    k_dil11   <<<EG1,NT,0,stream>>>(a,d2,cover,misb,Ls,&lcnt[r],Us,&rcnt[r-1],&rcnt[r-1],ep);
    k_dil21   <<<EG1,NT,0,stream>>>(a,d2,cover,Ls,&lcnt[r],&rcnt[r-1],ep);
    k_fincomp1<<<EG1,NT,0,stream>>>(a,b,cover,n,Ls,&lcnt[r],Ld,&lcnt[r+1],
                                    Us,&rcnt[r-1],Ud,&rcnt[r],&rcnt[r-1]);
  }

  // ---- cluster propagation (bitmask-filtered) ----
  k_cluster_init<<<NB,NT,0,stream>>>(misb,reach1b,a,b,n);
  k_chop1 <<<EG0,NT,0,stream>>>(b,misb,reach1b,row,col,E);
  k_chop2f<<<EG0,NT,0,stream>>>(a,b,reach1b,row,col,n,E);

  // ---- unique -> cluster ids ----
  k_mark <<<NB,NT,0,stream>>>(a,misb,present,scal,n);
  k_scan1<<<NBs,NT,0,stream>>>(present,n,bsum);
  k_scan2<<<1,NT,0,stream>>>(bsum,bscan,NBs,scal+1);
  k_scan3<<<NBs,NT,0,stream>>>(present,n,bscan,pref);
  k_assign<<<NB,NT,0,stream>>>(a,pref,cl,ccount,n);

  // ---- fill privatized dense copies ----
  k_fill_dense<<<2048,NT,0,stream>>>(dcopies,scal,CMsq);

  // ---- counting sort by cluster ----
  k_scan1<<<NBc,NT,0,stream>>>(ccount,CU_B,bsum);
  k_scan2<<<1,NT,0,stream>>>(bsum,bscan,NBc,nullptr);
  k_scan3<<<NBc,NT,0,stream>>>(ccount,CU_B,bscan,pref);
  k_scatter_nodes<<<NB,NT,0,stream>>>(cl,pref,cursor,nodeList,n);

  // ---- x_pooled ----
  k_pool_x<<<1024,NT,0,stream>>>(x,nodeList,pref,ccount,scal,(float*)d_out,(long)out_size);

  // ---- pooled adjacency ----
  k_edge_pool<<<EG0,NT,0,stream>>>(row,col,eattr,cl,scal,dcopies,E,CMsq);
  k_reduce_dense<<<1024,NT,0,stream>>>(dcopies,dense,scal,CMsq);
  k_cscan1<<<CB,NT,0,stream>>>(dense,scal,bsum,CMsq);
  k_scan2 <<<1,NT,0,stream>>>(bsum,bscan,CB,scal+2);
  k_cemit <<<CB,NT,0,stream>>>(dense,scal,bscan,(float*)d_out,(long)out_size,CMsq);
}

// Round 13
// 1730.206 us; speedup vs baseline: 1.1685x; 1.0287x over previous
//
#include <hip/hip_runtime.h>
#include <cmath>
#include <cstdint>

#define NT 256
#define EG0 1024          // grid for full-E passes
#define EG1 256           // grid for compacted passes
#define MAX_ROUND 16      // ~12 active rounds measured (round-2 FETCH accounting)
#define SCAN_T 32
#define SCAN_IPB (NT*SCAN_T)
#define SENT 0x80000000u  // -0.0f sentinel: fadd identity, survives copy-sum

// ---------- helpers ----------

__device__ __forceinline__ int getbit(const unsigned int* bm, int v){
  return (bm[v>>5]>>(v&31))&1u;
}
__device__ __forceinline__ void setbit(unsigned int* bm, int v){
  unsigned int m = 1u<<(v&31);
  if(!(bm[v>>5]&m)) atomicOr(&bm[v>>5], m);
}

__device__ __forceinline__ int block_append(int* cursor, bool pred, int* s_w){
  int wid  = threadIdx.x >> 6;
  int lane = threadIdx.x & 63;
  unsigned long long m = __ballot(pred);
  int cnt = __popcll(m);
  if(lane==0) s_w[wid]=cnt;
  __syncthreads();
  if(threadIdx.x==0){
    int t0=s_w[0], t1=s_w[1], t2=s_w[2], t3=s_w[3];
    int tot=t0+t1+t2+t3;
    int base = tot ? atomicAdd(cursor, tot) : 0;
    s_w[0]=base; s_w[1]=base+t0; s_w[2]=base+t0+t1; s_w[3]=base+t0+t1+t2;
  }
  __syncthreads();
  int pos = s_w[wid] + __popcll(m & ((1ull<<lane)-1ull));
  __syncthreads();
  return pos;
}

// ---------- init ----------

__global__ void k_init(int* a, int* b, int n){
  int v = blockIdx.x*NT + threadIdx.x;
  if(v<n){ a[v]=v; b[v]=v; }
}

__global__ void k_fill_dense(float* dcopies, const int* scal, long CMsq, int KC){
  long c = scal[0];
  long M = c*c; if(M>CMsq) M=CMsq;
  long stride = (long)gridDim.x*NT;
  for(long i = (long)blockIdx.x*NT + threadIdx.x; i<M; i+=stride){
    for(int k=0;k<KC;k++)
      ((unsigned int*)dcopies)[(long)k*CMsq + i] = SENT;
  }
}

// ---------- round 0 (full edge arrays) ----------

__global__ void k_hop0(int* b, const int* __restrict__ row,
                       const int* __restrict__ col, int E){
  int stride = gridDim.x*NT;
  for(int e = blockIdx.x*NT + threadIdx.x; e<E; e+=stride){
    int s = row[e];
    if(s < b[col[e]]) atomicMin(&b[col[e]], s);
  }
}

__global__ void k_hop0f(int* a, const int* b, const int* __restrict__ row,
                        const int* __restrict__ col, int n, int E){
  int stride = gridDim.x*NT;
  int total = n + E;
  for(int i = blockIdx.x*NT + threadIdx.x; i<total; i+=stride){
    if(i<n){
      if(b[i] < a[i]) atomicMin(&a[i], b[i]);
    } else {
      int e = i-n;
      int s = b[row[e]];
      if(s < a[col[e]]) atomicMin(&a[col[e]], s);
    }
  }
}

__global__ void k_dil0(const int* a, int* d2, int* cover, const int* __restrict__ row,
                       const int* __restrict__ col, int E, int ep){
  int stride = gridDim.x*NT;
  for(int e = blockIdx.x*NT + threadIdx.x; e<E; e+=stride){
    int r = row[e];
    if(a[r]==r){
      int cc = col[e];
      d2[r]=ep;  cover[r]=1;
      d2[cc]=ep; cover[cc]=1;
    }
  }
}

__global__ void k_dil20(const int* a, const int* d2, int* cover, const int* __restrict__ row,
                        const int* __restrict__ col, int E, int ep){
  int stride = gridDim.x*NT;
  for(int e = blockIdx.x*NT + threadIdx.x; e<E; e+=stride){
    int r = row[e];
    if((d2[r]==ep || a[r]==r) && !cover[col[e]]) cover[col[e]]=1;
  }
}

__global__ void k_fincomp0(int* a, int* b, unsigned int* misb, int* cover, int n,
                           const int* __restrict__ row, const int* __restrict__ col, int E,
                           int2* Ld, int* lcnt1, int* U1, int* rcnt0){
  __shared__ int s_w[4];
  long nth = (long)gridDim.x*NT;
  for(long base = (long)blockIdx.x*NT; base < n; base += nth){
    int v = (int)base + threadIdx.x;
    bool unc = false;
    if(v<n){
      int nw = (a[v]==v);
      if(nw){ setbit(misb,v); if(!cover[v]) cover[v]=1; }
      int cov = cover[v] | nw;
      int val = cov ? n : v;
      a[v]=val; b[v]=val;
      unc = !cov;
    }
    int pos = block_append(rcnt0, unc, s_w);
    if(unc) U1[pos]=v;
  }
  for(long base = (long)blockIdx.x*NT; base < E; base += nth){
    int e = (int)base + threadIdx.x;
    bool keep=false; int2 ed;
    if(e<E){
      ed = make_int2(row[e], col[e]);
      keep = (!cover[ed.x]) || (!cover[ed.y]);
    }
    int pos = block_append(lcnt1, keep, s_w);
    if(keep) Ld[pos]=ed;
  }
}

// ---------- rounds >=1 (compacted, gated) ----------

__global__ void k_hop1(int* b, const int* a, const int2* L, const int* pE,
                       const int* gate){
  if(*gate==0) return;
  int E = *pE;
  int stride = gridDim.x*NT;
  for(int e = blockIdx.x*NT + threadIdx.x; e<E; e+=stride){
    int2 ed = L[e];
    int s = a[ed.x];
    if(s < b[ed.y]) atomicMin(&b[ed.y], s);
  }
}

__global__ void k_hop1f(int* a, const int* b, const int2* L, const int* pE,
                        const int* U, const int* pU, const int* gate){
  if(*gate==0) return;
  int E = *pE, un = *pU;
  int total = un + E;
  int stride = gridDim.x*NT;
  for(int i = blockIdx.x*NT + threadIdx.x; i<total; i+=stride){
    if(i<un){
      int u = U[i];
      if(b[u] < a[u]) atomicMin(&a[u], b[u]);
    } else {
      int2 ed = L[i-un];
      int s = b[ed.x];
      if(s < a[ed.y]) atomicMin(&a[ed.y], s);
    }
  }
}

__global__ void k_dil11(const int* a, int* d2, int* cover, unsigned int* misb,
                        const int2* L, const int* pE, const int* U, const int* pU,
                        const int* gate, int ep){
  if(*gate==0) return;
  int E = *pE, un = *pU;
  int total = un + E;
  int stride = gridDim.x*NT;
  for(int i = blockIdx.x*NT + threadIdx.x; i<total; i+=stride){
    if(i<un){
      int u = U[i];
      if(a[u]==u){ setbit(misb,u); cover[u]=1; d2[u]=ep; }
    } else {
      int2 ed = L[i-un];
      if(a[ed.x]==ed.x){ d2[ed.x]=ep; cover[ed.x]=1; d2[ed.y]=ep; cover[ed.y]=1; }
    }
  }
}

__global__ void k_dil21(const int* a, const int* d2, int* cover, const int2* L,
                        const int* pE, const int* gate, int ep){
  if(*gate==0) return;
  int E = *pE;
  int stride = gridDim.x*NT;
  for(int e = blockIdx.x*NT + threadIdx.x; e<E; e+=stride){
    int2 ed = L[e];
    if((d2[ed.x]==ep || a[ed.x]==ed.x) && !cover[ed.y]) cover[ed.y]=1;
  }
}

__global__ void k_fincomp1(int* a, int* b, const int* cover, int n,
                           const int2* Ls, const int* pE, int2* Ld, int* lcntD,
                           const int* Us, const int* pU, int* Ud, int* rcntD,
                           const int* gate){
  if(*gate==0) return;
  __shared__ int s_w[4];
  int E = *pE, un = *pU;
  long nth = (long)gridDim.x*NT;
  for(long base = (long)blockIdx.x*NT; base < un; base += nth){
    int i = (int)base + threadIdx.x;
    bool unc=false; int u=0;
    if(i<un){ u = Us[i]; unc = !cover[u]; }
    int pos = block_append(rcntD, unc, s_w);
    if(unc) Ud[pos]=u;
  }
  for(long base = (long)blockIdx.x*NT; base < E; base += nth){
    int e = (int)base + threadIdx.x;
    bool keep=false; int2 ed;
    if(e<E){
      ed = Ls[e];
      int vx = cover[ed.x] ? n : ed.x;  a[ed.x]=vx; b[ed.x]=vx;
      int vy = cover[ed.y] ? n : ed.y;  a[ed.y]=vy; b[ed.y]=vy;
      keep = (!cover[ed.x]) || (!cover[ed.y]);
    }
    int pos = block_append(lcntD, keep, s_w);
    if(keep) Ld[pos]=ed;
  }
}

// ---------- cluster phase (bitmask-filtered) ----------

__global__ void k_cluster_init(const unsigned int* misb, unsigned int* reach1b,
                               int* a, int* b, int n){
  int v = blockIdx.x*NT + threadIdx.x;
  if(v<n){
    int m = getbit(misb,v);
    int val = m ? v : n;
    a[v]=val; b[v]=val;
    if(m) setbit(reach1b,v);
  }
}

__global__ void k_chop1(int* b, const unsigned int* misb, unsigned int* reach1b,
                        const int* __restrict__ row, const int* __restrict__ col, int E){
  int stride = gridDim.x*NT;
  for(int e = blockIdx.x*NT + threadIdx.x; e<E; e+=stride){
    int r = row[e];
    if(getbit(misb,r)){
      int cc = col[e];
      if(r < b[cc]) atomicMin(&b[cc], r);
      setbit(reach1b, cc);
    }
  }
}

__global__ void k_chop2f(int* a, const int* b, const unsigned int* reach1b,
                         const int* __restrict__ row, const int* __restrict__ col,
                         int n, int E){
  int stride = gridDim.x*NT;
  int total = n + E;
  for(int i = blockIdx.x*NT + threadIdx.x; i<total; i+=stride){
    if(i<n){
      if(b[i] < a[i]) atomicMin(&a[i], b[i]);
    } else {
      int e = i-n;
      int r = row[e];
      if(getbit(reach1b,r)){
        int s = b[r];
        if(s < n && s < a[col[e]]) atomicMin(&a[col[e]], s);
      }
    }
  }
}

__global__ void k_mark(const int* mr, const unsigned int* misb, int* present, int* cmis, int n){
  int v = blockIdx.x*NT + threadIdx.x;
  int m = 0;
  if(v<n){
    int r = mr[v];
    if(r<n && !present[r]) present[r]=1;
    m = getbit(misb,v);
  }
  __shared__ int sh[NT];
  sh[threadIdx.x]=m; __syncthreads();
  for(int off=NT/2; off>0; off>>=1){
    if(threadIdx.x<off) sh[threadIdx.x]+=sh[threadIdx.x+off];
    __syncthreads();
  }
  if(threadIdx.x==0 && sh[0]) atomicAdd(cmis, sh[0]);
}

// ---------- generic scan ----------

__global__ void k_scan1(const int* A, int M, int* bsum){
  int t = threadIdx.x;
  long base = (long)blockIdx.x*SCAN_IPB + (long)t*SCAN_T;
  int s = 0;
  #pragma unroll
  for(int j=0;j<SCAN_T;j++){ long i=base+j; if(i<M) s += A[i]; }
  __shared__ int sh[NT];
  sh[t]=s; __syncthreads();
  for(int off=NT/2; off>0; off>>=1){ if(t<off) sh[t]+=sh[t+off]; __syncthreads(); }
  if(t==0) bsum[blockIdx.x]=sh[0];
}

__global__ void k_scan2(const int* bsum, int* bscan, int B, int* totalOut){
  __shared__ int sh[NT];
  int t = threadIdx.x;
  int carry = 0;
  for(int base=0; base<B; base+=NT){
    int i = base+t;
    int v = (i<B) ? bsum[i] : 0;
    sh[t]=v; __syncthreads();
    for(int off=1; off<NT; off<<=1){
      int x=0; if(t>=off) x=sh[t-off];
      __syncthreads();
      sh[t]+=x; __syncthreads();
    }
    int incl = sh[t];
    if(i<B) bscan[i] = carry + incl - v;
    carry += sh[NT-1];
    __syncthreads();
  }
  if(t==0 && totalOut) *totalOut = carry;
}

__global__ void k_scan3(const int* A, int M, const int* bscan, int* pref){
  int t = threadIdx.x;
  long base = (long)blockIdx.x*SCAN_IPB + (long)t*SCAN_T;
  int s = 0;
  #pragma unroll
  for(int j=0;j<SCAN_T;j++){ long i=base+j; if(i<M) s += A[i]; }
  __shared__ int sh[NT];
  sh[t]=s; __syncthreads();
  for(int off=1; off<NT; off<<=1){
    int x=0; if(t>=off) x=sh[t-off];
    __syncthreads();
    sh[t]+=x; __syncthreads();
  }
  int run = bscan[blockIdx.x] + (sh[t]-s);
  for(int j=0;j<SCAN_T;j++){
    long i=base+j;
    if(i<M){ pref[i]=run; run += A[i]; }
  }
}

// ---------- clustering & pooling ----------

__global__ void k_assign(const int* mr, const int* pref, int* cl, int* ccount, int n){
  int v = blockIdx.x*NT + threadIdx.x;
  if(v<n){
    int r = mr[v];
    int cid = (r<n) ? pref[r] : 0;
    cl[v]=cid;
    atomicAdd(&ccount[cid],1);
  }
}

__global__ void k_scatter_nodes(const int* cl, const int* cstart, int* cursor, int* nodeList, int n){
  int v = blockIdx.x*NT + threadIdx.x;
  if(v<n){
    int cid = cl[v];
    int pos = cstart[cid] + atomicAdd(&cursor[cid],1);
    nodeList[pos]=v;
  }
}

// 4 segments per cluster -> c*4 blocks (~9 waves/SIMD vs 2.3), partials to ws
__global__ void k_pool_seg(const float* __restrict__ x, const int* nodeList, const int* cstart,
                           const int* ccount, const int* scal, float* part, long partStride){
  int c = scal[0], U = scal[1];
  int t = threadIdx.x;
  int total = c*4;
  for(int idx = blockIdx.x; idx < total; idx += gridDim.x){
    int cid = idx>>2, seg = idx&3;
    float s0=0.f,s1=0.f,s2=0.f,s3=0.f,s4=0.f,s5=0.f,s6=0.f,s7=0.f;
    if(cid<U){
      int st = cstart[cid], cn = ccount[cid];
      int q  = (cn+3)>>2;
      int lo = seg*q, hi = lo+q; if(hi>cn) hi=cn;
      int i=lo;
      for(; i+7<hi; i+=8){
        int n0=nodeList[st+i],   n1=nodeList[st+i+1], n2=nodeList[st+i+2], n3=nodeList[st+i+3];
        int n4=nodeList[st+i+4], n5=nodeList[st+i+5], n6=nodeList[st+i+6], n7=nodeList[st+i+7];
        s0 += x[(size_t)n0*256 + t]; s1 += x[(size_t)n1*256 + t];
        s2 += x[(size_t)n2*256 + t]; s3 += x[(size_t)n3*256 + t];
        s4 += x[(size_t)n4*256 + t]; s5 += x[(size_t)n5*256 + t];
        s6 += x[(size_t)n6*256 + t]; s7 += x[(size_t)n7*256 + t];
      }
      for(; i<hi; i++) s0 += x[(size_t)nodeList[st+i]*256 + t];
      s0 += s1+s2+s3+s4+s5+s6+s7;
    }
    part[(long)seg*partStride + (long)cid*256 + t] = s0;
  }
}

__global__ void k_pool_add(const float* __restrict__ part, long partStride,
                           const int* scal, float* out, long out_size){
  int c = scal[0];
  long M = (long)c*256;
  long stride = (long)gridDim.x*NT;
  for(long i = (long)blockIdx.x*NT + threadIdx.x; i<M; i+=stride){
    float s = part[i] + part[partStride+i] + part[2L*partStride+i] + part[3L*partStride+i];
    if(i < out_size) out[i]=s;
  }
}

// one fp32 atomic per edge into a runtime-KC privatized copy
__global__ void k_edge_pool(const int* __restrict__ row, const int* __restrict__ col,
                            const float* __restrict__ attr, const int* cl,
                            const int* scal, float* dcopies, int E, long CMsq, int KC){
  int c = scal[0];
  float* dc = dcopies + (long)(blockIdx.x % KC)*CMsq;
  int stride = gridDim.x*NT;
  for(int e = blockIdx.x*NT + threadIdx.x; e<E; e+=stride){
    long key = (long)cl[row[e]]*c + cl[col[e]];
    if(key < CMsq){
      unsafeAtomicAdd(&dc[key], attr[e]);
    }
  }
}

__global__ void k_reduce_dense(const float* __restrict__ dcopies, float* dense,
                               const int* scal, long CMsq, int KC){
  long c = scal[0];
  long M = c*c; if(M>CMsq) M=CMsq;
  long stride = (long)gridDim.x*NT;
  for(long i = (long)blockIdx.x*NT + threadIdx.x; i<M; i+=stride){
    float s = dcopies[i];
    for(int k=1;k<KC;k++) s += dcopies[(long)k*CMsq + i];
    dense[i]=s;
  }
}

__device__ __forceinline__ int cellp(const float* dense, long i){
  return __float_as_uint(dense[i]) != SENT;
}

__global__ void k_cscan1(const float* dense, const int* scal, int* bsum, long CMsq){
  int c = scal[0];
  long M = (long)c*c; if(M>CMsq) M=CMsq;
  int t = threadIdx.x;
  long base = (long)blockIdx.x*SCAN_IPB + (long)t*SCAN_T;
  int s = 0;
  if(base < M && c > 0){
    int r = (int)(base / c);
    int q = (int)(base - (long)r*c);
    for(int j=0;j<SCAN_T;j++){
      long i=base+j;
      if(i<M){
        if(cellp(dense,i) && r!=q) s++;
      }
      if(++q==c){ q=0; r++; }
    }
  }
  __shared__ int sh[NT];
  sh[t]=s; __syncthreads();
  for(int off=NT/2; off>0; off>>=1){ if(t<off) sh[t]+=sh[t+off]; __syncthreads(); }
  if(t==0) bsum[blockIdx.x]=sh[0];
}

__global__ void k_cemit(const float* dense, const int* scal,
                        const int* bscan, float* out, long out_size, long CMsq){
  int c = scal[0]; int P = scal[2];
  long M = (long)c*c; if(M>CMsq) M=CMsq;
  long xoff = (long)c*256;
  int t = threadIdx.x;
  long base = (long)blockIdx.x*SCAN_IPB + (long)t*SCAN_T;
  int s = 0;
  int r0=0,q0=0;
  if(base < M && c > 0){
    r0 = (int)(base / c);
    q0 = (int)(base - (long)r0*c);
    int r=r0, q=q0;
    for(int j=0;j<SCAN_T;j++){
      long i=base+j;
      if(i<M){
        if(cellp(dense,i) && r!=q) s++;
      }
      if(++q==c){ q=0; r++; }
    }
  }
  __shared__ int sh[NT];
  sh[t]=s; __syncthreads();
  for(int off=1; off<NT; off<<=1){
    int x=0; if(t>=off) x=sh[t-off];
    __syncthreads();
    sh[t]+=x; __syncthreads();
  }
  int run = bscan[blockIdx.x] + (sh[t]-s);
  if(base < M && c > 0){
    int r=r0, q=q0;
    for(int j=0;j<SCAN_T;j++){
      long i=base+j;
      if(i<M && cellp(dense,i) && r!=q){
        long o0 = xoff + run;
        long o1 = xoff + (long)P + run;
        long o2 = xoff + 2L*(long)P + run;
        if(o0<out_size) out[o0]=(float)r;
        if(o1<out_size) out[o1]=(float)q;
        if(o2<out_size) out[o2]=dense[i];
        run++;
      }
      if(++q==c){ q=0; r++; }
    }
  }
}

// ---------- host ----------

extern "C" void kernel_launch(void* const* d_in, const int* in_sizes, int n_in,
                              void* d_out, int out_size, void* d_ws, size_t ws_size,
                              hipStream_t stream){
  (void)n_in;
  const float* x     = (const float*)d_in[0];
  const int*   eidx  = (const int*)d_in[1];
  const float* eattr = (const float*)d_in[2];
  const int D = 256;
  int n = in_sizes[0]/D;
  int E = in_sizes[1]/2;
  const int* row = eidx;
  const int* col = eidx + E;
  int nwords = (n+31)>>5;
  int CU_B = out_size/256 + 1; if(CU_B > n) CU_B = n;   // host-known bound: c <= CU_B

  char* p = (char*)d_ws;
  auto alloc = [&](size_t bytes)->char*{ char* r=p; p += (bytes+255)&~(size_t)255; return r; };
  int2* LA   = (int2*)alloc((size_t)E*8);
  int2* LB   = (int2*)alloc((size_t)E*8);
  int* a     = (int*)alloc((size_t)n*4);
  int* b     = (int*)alloc((size_t)n*4);
  int* cl    = (int*)alloc((size_t)n*4);
  int* nodeList = (int*)alloc((size_t)n*4);
  int* pref  = (int*)alloc((size_t)n*4);
  int* U1    = (int*)alloc((size_t)n*4);
  int* U2    = (int*)alloc((size_t)n*4);
  int* bsum  = (int*)alloc(4096*4);
  int* bscan = (int*)alloc(4096*4);
  char* zstart = p;                         // zeroed each call
  int* cover   = (int*)alloc((size_t)n*4);
  int* d2      = (int*)alloc((size_t)n*4);
  unsigned int* misb    = (unsigned int*)alloc((size_t)nwords*4);
  unsigned int* reach1b = (unsigned int*)alloc((size_t)nwords*4);
  int* present = (int*)alloc((size_t)n*4);
  int* ccount  = (int*)alloc((size_t)n*4);
  int* cursor  = (int*)alloc((size_t)n*4);
  int* rcnt    = (int*)alloc((MAX_ROUND+2)*4);
  int* lcnt    = (int*)alloc((MAX_ROUND+2)*4);
  int* scal    = (int*)alloc(64);              // [0]=c, [1]=U, [2]=P
  size_t zbytes = (size_t)(p - zstart);

  long partStride = (long)CU_B*256;
  float* part = (float*)alloc((size_t)4*partStride*4);   // 4 segment partials

  size_t used   = (size_t)(p-(char*)d_ws);
  size_t remain = (ws_size > used+4096) ? ws_size-used-4096 : 0;
  long CM = CU_B;
  long CMsq = CM*CM;
  // dynamic copy count: as many privatized copies as fit (plus 1 for reduce target)
  int KC = (int)(remain/(4*(size_t)CMsq)) - 1;
  if(KC > 8) KC = 8;
  if(KC < 1){
    KC = 1;
    while(CM>1 && (size_t)(KC+1)*CM*CM*4 > remain) CM--;   // last-resort fallback
    CMsq = CM*CM;
  }
  float* dcopies = (float*)alloc((size_t)KC*CMsq*4);
  float* dense   = (float*)alloc((size_t)CMsq*4);

  hipMemsetAsync(zstart, 0, zbytes, stream);

  int NB  = (n+NT-1)/NT;
  int NBs = (n+SCAN_IPB-1)/SCAN_IPB;
  int NBc = (CU_B+SCAN_IPB-1)/SCAN_IPB;
  int CB  = (int)((CMsq+SCAN_IPB-1)/SCAN_IPB);
  if(CB>4096) CB=4096;

  // ---- round 0 (full graph) ----
  k_init    <<<NB,NT,0,stream>>>(a,b,n);
  k_hop0    <<<EG0,NT,0,stream>>>(b,row,col,E);
  k_hop0f   <<<EG0,NT,0,stream>>>(a,b,row,col,n,E);
  k_dil0    <<<EG0,NT,0,stream>>>(a,d2,cover,row,col,E,1);
  k_dil20   <<<EG0,NT,0,stream>>>(a,d2,cover,row,col,E,1);
  k_fincomp0<<<EG0,NT,0,stream>>>(a,b,misb,cover,n,row,col,E,LB,&lcnt[1],U1,&rcnt[0]);

  // ---- rounds 1..MAX_ROUND-1 (compacted, gated) ----
  for(int r=1; r<MAX_ROUND; ++r){
    int2* Ls = (r&1) ? LB : LA;
    int2* Ld = (r&1) ? LA : LB;
    int*  Us = (r&1) ? U1 : U2;
    int*  Ud = (r&1) ? U2 : U1;
    int ep = r+1;
    k_hop1    <<<EG1,NT,0,stream>>>(b,a,Ls,&lcnt[r],&rcnt[r-1]);
    k_hop1f   <<<EG1,NT,0,stream>>>(a,b,Ls,&lcnt[r],Us,&rcnt[r-1],&rcnt[r-1]);
    k_dil11   <<<EG1,NT,0,stream>>>(a,d2,cover,misb,Ls,&lcnt[r],Us,&rcnt[r-1],&rcnt[r-1],ep);
    k_dil21   <<<EG1,NT,0,stream>>>(a,d2,cover,Ls,&lcnt[r],&rcnt[r-1],ep);
    k_fincomp1<<<EG1,NT,0,stream>>>(a,b,cover,n,Ls,&lcnt[r],Ld,&lcnt[r+1],
                                    Us,&rcnt[r-1],Ud,&rcnt[r],&rcnt[r-1]);
  }

  // ---- cluster propagation (bitmask-filtered) ----
  k_cluster_init<<<NB,NT,0,stream>>>(misb,reach1b,a,b,n);
  k_chop1 <<<EG0,NT,0,stream>>>(b,misb,reach1b,row,col,E);
  k_chop2f<<<EG0,NT,0,stream>>>(a,b,reach1b,row,col,n,E);

  // ---- unique -> cluster ids ----
  k_mark <<<NB,NT,0,stream>>>(a,misb,present,scal,n);
  k_scan1<<<NBs,NT,0,stream>>>(present,n,bsum);
  k_scan2<<<1,NT,0,stream>>>(bsum,bscan,NBs,scal+1);
  k_scan3<<<NBs,NT,0,stream>>>(present,n,bscan,pref);
  k_assign<<<NB,NT,0,stream>>>(a,pref,cl,ccount,n);

  // ---- fill privatized dense copies ----
  k_fill_dense<<<2048,NT,0,stream>>>(dcopies,scal,CMsq,KC);

  // ---- counting sort by cluster ----
  k_scan1<<<NBc,NT,0,stream>>>(ccount,CU_B,bsum);
  k_scan2<<<1,NT,0,stream>>>(bsum,bscan,NBc,nullptr);
  k_scan3<<<NBc,NT,0,stream>>>(ccount,CU_B,bscan,pref);
  k_scatter_nodes<<<NB,NT,0,stream>>>(cl,pref,cursor,nodeList,n);

  // ---- x_pooled: 4-segment partials + add ----
  k_pool_seg<<<2048,NT,0,stream>>>(x,nodeList,pref,ccount,scal,part,partStride);
  k_pool_add<<<256,NT,0,stream>>>(part,partStride,scal,(float*)d_out,(long)out_size);

  // ---- pooled adjacency ----
  k_edge_pool<<<EG0,NT,0,stream>>>(row,col,eattr,cl,scal,dcopies,E,CMsq,KC);
  k_reduce_dense<<<1024,NT,0,stream>>>(dcopies,dense,scal,CMsq,KC);
  k_cscan1<<<CB,NT,0,stream>>>(dense,scal,bsum,CMsq);
  k_scan2 <<<1,NT,0,stream>>>(bsum,bscan,CB,scal+2);
  k_cemit <<<CB,NT,0,stream>>>(dense,scal,bscan,(float*)d_out,(long)out_size,CMsq);
}

// Round 14
// 1727.089 us; speedup vs baseline: 1.1706x; 1.0018x over previous
//
#include <hip/hip_runtime.h>
#include <cmath>
#include <cstdint>

#define NT 256
#define EG0 2048          // full-E passes: 2048 blk x 4 waves = 8192 waves = 100% occ
#define EGP 1024          // edge_pool: atomic-pipe bound, grid-insensitive (r9)
#define EG1 256           // small compacted rounds
#define EG1B 1024         // rounds 1-2 (still ~1M-edge lists)
#define MAX_ROUND 16
#define SCAN_T 32
#define SCAN_IPB (NT*SCAN_T)
#define SENT 0x80000000u  // -0.0f sentinel: fadd identity, survives copy-sum

// ---------- helpers ----------

__device__ __forceinline__ int getbit(const unsigned int* bm, int v){
  return (bm[v>>5]>>(v&31))&1u;
}
__device__ __forceinline__ void setbit(unsigned int* bm, int v){
  unsigned int m = 1u<<(v&31);
  if(!(bm[v>>5]&m)) atomicOr(&bm[v>>5], m);
}

__device__ __forceinline__ int block_append(int* cursor, bool pred, int* s_w){
  int wid  = threadIdx.x >> 6;
  int lane = threadIdx.x & 63;
  unsigned long long m = __ballot(pred);
  int cnt = __popcll(m);
  if(lane==0) s_w[wid]=cnt;
  __syncthreads();
  if(threadIdx.x==0){
    int t0=s_w[0], t1=s_w[1], t2=s_w[2], t3=s_w[3];
    int tot=t0+t1+t2+t3;
    int base = tot ? atomicAdd(cursor, tot) : 0;
    s_w[0]=base; s_w[1]=base+t0; s_w[2]=base+t0+t1; s_w[3]=base+t0+t1+t2;
  }
  __syncthreads();
  int pos = s_w[wid] + __popcll(m & ((1ull<<lane)-1ull));
  __syncthreads();
  return pos;
}

// ---------- init ----------

__global__ void k_init(int* a, int* b, int n){
  int v = blockIdx.x*NT + threadIdx.x;
  if(v<n){ a[v]=v; b[v]=v; }
}

__global__ void k_fill_dense(float* dcopies, const int* scal, long CMsq, int KC){
  long c = scal[0];
  long M = c*c; if(M>CMsq) M=CMsq;
  long stride = (long)gridDim.x*NT;
  for(long i = (long)blockIdx.x*NT + threadIdx.x; i<M; i+=stride){
    for(int k=0;k<KC;k++)
      ((unsigned int*)dcopies)[(long)k*CMsq + i] = SENT;
  }
}

// ---------- round 0 (full edge arrays) ----------

__global__ void k_hop0(int* b, const int* __restrict__ row,
                       const int* __restrict__ col, int E){
  int stride = gridDim.x*NT;
  for(int e = blockIdx.x*NT + threadIdx.x; e<E; e+=stride){
    int s = row[e];
    if(s < b[col[e]]) atomicMin(&b[col[e]], s);
  }
}

__global__ void k_hop0f(int* a, const int* b, const int* __restrict__ row,
                        const int* __restrict__ col, int n, int E){
  int stride = gridDim.x*NT;
  int total = n + E;
  for(int i = blockIdx.x*NT + threadIdx.x; i<total; i+=stride){
    if(i<n){
      if(b[i] < a[i]) atomicMin(&a[i], b[i]);
    } else {
      int e = i-n;
      int s = b[row[e]];
      if(s < a[col[e]]) atomicMin(&a[col[e]], s);
    }
  }
}

__global__ void k_dil0(const int* a, int* d2, int* cover, const int* __restrict__ row,
                       const int* __restrict__ col, int E, int ep){
  int stride = gridDim.x*NT;
  for(int e = blockIdx.x*NT + threadIdx.x; e<E; e+=stride){
    int r = row[e];
    if(a[r]==r){
      int cc = col[e];
      d2[r]=ep;  cover[r]=1;
      d2[cc]=ep; cover[cc]=1;
    }
  }
}

__global__ void k_dil20(const int* a, const int* d2, int* cover, const int* __restrict__ row,
                        const int* __restrict__ col, int E, int ep){
  int stride = gridDim.x*NT;
  for(int e = blockIdx.x*NT + threadIdx.x; e<E; e+=stride){
    int r = row[e];
    if((d2[r]==ep || a[r]==r) && !cover[col[e]]) cover[col[e]]=1;
  }
}

__global__ void k_fincomp0(int* a, int* b, unsigned int* misb, int* cover, int n,
                           const int* __restrict__ row, const int* __restrict__ col, int E,
                           int2* Ld, int* lcnt1, int* U1, int* rcnt0){
  __shared__ int s_w[4];
  long nth = (long)gridDim.x*NT;
  for(long base = (long)blockIdx.x*NT; base < n; base += nth){
    int v = (int)base + threadIdx.x;
    bool unc = false;
    if(v<n){
      int nw = (a[v]==v);
      if(nw){ setbit(misb,v); if(!cover[v]) cover[v]=1; }
      int cov = cover[v] | nw;
      int val = cov ? n : v;
      a[v]=val; b[v]=val;
      unc = !cov;
    }
    int pos = block_append(rcnt0, unc, s_w);
    if(unc) U1[pos]=v;
  }
  for(long base = (long)blockIdx.x*NT; base < E; base += nth){
    int e = (int)base + threadIdx.x;
    bool keep=false; int2 ed;
    if(e<E){
      ed = make_int2(row[e], col[e]);
      keep = (!cover[ed.x]) || (!cover[ed.y]);
    }
    int pos = block_append(lcnt1, keep, s_w);
    if(keep) Ld[pos]=ed;
  }
}

// ---------- rounds >=1 (compacted, gated) ----------

__global__ void k_hop1(int* b, const int* a, const int2* L, const int* pE,
                       const int* gate){
  if(*gate==0) return;
  int E = *pE;
  int stride = gridDim.x*NT;
  for(int e = blockIdx.x*NT + threadIdx.x; e<E; e+=stride){
    int2 ed = L[e];
    int s = a[ed.x];
    if(s < b[ed.y]) atomicMin(&b[ed.y], s);
  }
}

__global__ void k_hop1f(int* a, const int* b, const int2* L, const int* pE,
                        const int* U, const int* pU, const int* gate){
  if(*gate==0) return;
  int E = *pE, un = *pU;
  int total = un + E;
  int stride = gridDim.x*NT;
  for(int i = blockIdx.x*NT + threadIdx.x; i<total; i+=stride){
    if(i<un){
      int u = U[i];
      if(b[u] < a[u]) atomicMin(&a[u], b[u]);
    } else {
      int2 ed = L[i-un];
      int s = b[ed.x];
      if(s < a[ed.y]) atomicMin(&a[ed.y], s);
    }
  }
}

__global__ void k_dil11(const int* a, int* d2, int* cover, unsigned int* misb,
                        const int2* L, const int* pE, const int* U, const int* pU,
                        const int* gate, int ep){
  if(*gate==0) return;
  int E = *pE, un = *pU;
  int total = un + E;
  int stride = gridDim.x*NT;
  for(int i = blockIdx.x*NT + threadIdx.x; i<total; i+=stride){
    if(i<un){
      int u = U[i];
      if(a[u]==u){ setbit(misb,u); cover[u]=1; d2[u]=ep; }
    } else {
      int2 ed = L[i-un];
      if(a[ed.x]==ed.x){ d2[ed.x]=ep; cover[ed.x]=1; d2[ed.y]=ep; cover[ed.y]=1; }
    }
  }
}

__global__ void k_dil21(const int* a, const int* d2, int* cover, const int2* L,
                        const int* pE, const int* gate, int ep){
  if(*gate==0) return;
  int E = *pE;
  int stride = gridDim.x*NT;
  for(int e = blockIdx.x*NT + threadIdx.x; e<E; e+=stride){
    int2 ed = L[e];
    if((d2[ed.x]==ep || a[ed.x]==ed.x) && !cover[ed.y]) cover[ed.y]=1;
  }
}

__global__ void k_fincomp1(int* a, int* b, const int* cover, int n,
                           const int2* Ls, const int* pE, int2* Ld, int* lcntD,
                           const int* Us, const int* pU, int* Ud, int* rcntD,
                           const int* gate){
  if(*gate==0) return;
  __shared__ int s_w[4];
  int E = *pE, un = *pU;
  long nth = (long)gridDim.x*NT;
  for(long base = (long)blockIdx.x*NT; base < un; base += nth){
    int i = (int)base + threadIdx.x;
    bool unc=false; int u=0;
    if(i<un){ u = Us[i]; unc = !cover[u]; }
    int pos = block_append(rcntD, unc, s_w);
    if(unc) Ud[pos]=u;
  }
  for(long base = (long)blockIdx.x*NT; base < E; base += nth){
    int e = (int)base + threadIdx.x;
    bool keep=false; int2 ed;
    if(e<E){
      ed = Ls[e];
      int vx = cover[ed.x] ? n : ed.x;  a[ed.x]=vx; b[ed.x]=vx;
      int vy = cover[ed.y] ? n : ed.y;  a[ed.y]=vy; b[ed.y]=vy;
      keep = (!cover[ed.x]) || (!cover[ed.y]);
    }
    int pos = block_append(lcntD, keep, s_w);
    if(keep) Ld[pos]=ed;
  }
}

// ---------- cluster phase (bitmask-filtered) ----------

__global__ void k_cluster_init(const unsigned int* misb, unsigned int* reach1b,
                               int* a, int* b, int n){
  int v = blockIdx.x*NT + threadIdx.x;
  if(v<n){
    int m = getbit(misb,v);
    int val = m ? v : n;
    a[v]=val; b[v]=val;
    if(m) setbit(reach1b,v);
  }
}

__global__ void k_chop1(int* b, const unsigned int* misb, unsigned int* reach1b,
                        const int* __restrict__ row, const int* __restrict__ col, int E){
  int stride = gridDim.x*NT;
  for(int e = blockIdx.x*NT + threadIdx.x; e<E; e+=stride){
    int r = row[e];
    if(getbit(misb,r)){
      int cc = col[e];
      if(r < b[cc]) atomicMin(&b[cc], r);
      setbit(reach1b, cc);
    }
  }
}

__global__ void k_chop2f(int* a, const int* b, const unsigned int* reach1b,
                         const int* __restrict__ row, const int* __restrict__ col,
                         int n, int E){
  int stride = gridDim.x*NT;
  int total = n + E;
  for(int i = blockIdx.x*NT + threadIdx.x; i<total; i+=stride){
    if(i<n){
      if(b[i] < a[i]) atomicMin(&a[i], b[i]);
    } else {
      int e = i-n;
      int r = row[e];
      if(getbit(reach1b,r)){
        int s = b[r];
        if(s < n && s < a[col[e]]) atomicMin(&a[col[e]], s);
      }
    }
  }
}

__global__ void k_mark(const int* mr, const unsigned int* misb, int* present, int* cmis, int n){
  int v = blockIdx.x*NT + threadIdx.x;
  int m = 0;
  if(v<n){
    int r = mr[v];
    if(r<n && !present[r]) present[r]=1;
    m = getbit(misb,v);
  }
  __shared__ int sh[NT];
  sh[threadIdx.x]=m; __syncthreads();
  for(int off=NT/2; off>0; off>>=1){
    if(threadIdx.x<off) sh[threadIdx.x]+=sh[threadIdx.x+off];
    __syncthreads();
  }
  if(threadIdx.x==0 && sh[0]) atomicAdd(cmis, sh[0]);
}

// ---------- generic scan ----------

__global__ void k_scan1(const int* A, int M, int* bsum){
  int t = threadIdx.x;
  long base = (long)blockIdx.x*SCAN_IPB + (long)t*SCAN_T;
  int s = 0;
  #pragma unroll
  for(int j=0;j<SCAN_T;j++){ long i=base+j; if(i<M) s += A[i]; }
  __shared__ int sh[NT];
  sh[t]=s; __syncthreads();
  for(int off=NT/2; off>0; off>>=1){ if(t<off) sh[t]+=sh[t+off]; __syncthreads(); }
  if(t==0) bsum[blockIdx.x]=sh[0];
}

__global__ void k_scan2(const int* bsum, int* bscan, int B, int* totalOut){
  __shared__ int sh[NT];
  int t = threadIdx.x;
  int carry = 0;
  for(int base=0; base<B; base+=NT){
    int i = base+t;
    int v = (i<B) ? bsum[i] : 0;
    sh[t]=v; __syncthreads();
    for(int off=1; off<NT; off<<=1){
      int x=0; if(t>=off) x=sh[t-off];
      __syncthreads();
      sh[t]+=x; __syncthreads();
    }
    int incl = sh[t];
    if(i<B) bscan[i] = carry + incl - v;
    carry += sh[NT-1];
    __syncthreads();
  }
  if(t==0 && totalOut) *totalOut = carry;
}

__global__ void k_scan3(const int* A, int M, const int* bscan, int* pref){
  int t = threadIdx.x;
  long base = (long)blockIdx.x*SCAN_IPB + (long)t*SCAN_T;
  int s = 0;
  #pragma unroll
  for(int j=0;j<SCAN_T;j++){ long i=base+j; if(i<M) s += A[i]; }
  __shared__ int sh[NT];
  sh[t]=s; __syncthreads();
  for(int off=1; off<NT; off<<=1){
    int x=0; if(t>=off) x=sh[t-off];
    __syncthreads();
    sh[t]+=x; __syncthreads();
  }
  int run = bscan[blockIdx.x] + (sh[t]-s);
  for(int j=0;j<SCAN_T;j++){
    long i=base+j;
    if(i<M){ pref[i]=run; run += A[i]; }
  }
}

// ---------- clustering & pooling ----------

__global__ void k_assign(const int* mr, const int* pref, int* cl, int* ccount, int n){
  int v = blockIdx.x*NT + threadIdx.x;
  if(v<n){
    int r = mr[v];
    int cid = (r<n) ? pref[r] : 0;
    cl[v]=cid;
    atomicAdd(&ccount[cid],1);
  }
}

__global__ void k_scatter_nodes(const int* cl, const int* cstart, int* cursor, int* nodeList, int n){
  int v = blockIdx.x*NT + threadIdx.x;
  if(v<n){
    int cid = cl[v];
    int pos = cstart[cid] + atomicAdd(&cursor[cid],1);
    nodeList[pos]=v;
  }
}

// 4 segments per cluster, partials to ws
__global__ void k_pool_seg(const float* __restrict__ x, const int* nodeList, const int* cstart,
                           const int* ccount, const int* scal, float* part, long partStride){
  int c = scal[0], U = scal[1];
  int t = threadIdx.x;
  int total = c*4;
  for(int idx = blockIdx.x; idx < total; idx += gridDim.x){
    int cid = idx>>2, seg = idx&3;
    float s0=0.f,s1=0.f,s2=0.f,s3=0.f,s4=0.f,s5=0.f,s6=0.f,s7=0.f;
    if(cid<U){
      int st = cstart[cid], cn = ccount[cid];
      int q  = (cn+3)>>2;
      int lo = seg*q, hi = lo+q; if(hi>cn) hi=cn;
      int i=lo;
      for(; i+7<hi; i+=8){
        int n0=nodeList[st+i],   n1=nodeList[st+i+1], n2=nodeList[st+i+2], n3=nodeList[st+i+3];
        int n4=nodeList[st+i+4], n5=nodeList[st+i+5], n6=nodeList[st+i+6], n7=nodeList[st+i+7];
        s0 += x[(size_t)n0*256 + t]; s1 += x[(size_t)n1*256 + t];
        s2 += x[(size_t)n2*256 + t]; s3 += x[(size_t)n3*256 + t];
        s4 += x[(size_t)n4*256 + t]; s5 += x[(size_t)n5*256 + t];
        s6 += x[(size_t)n6*256 + t]; s7 += x[(size_t)n7*256 + t];
      }
      for(; i<hi; i++) s0 += x[(size_t)nodeList[st+i]*256 + t];
      s0 += s1+s2+s3+s4+s5+s6+s7;
    }
    part[(long)seg*partStride + (long)cid*256 + t] = s0;
  }
}

__global__ void k_pool_add(const float* __restrict__ part, long partStride,
                           const int* scal, float* out, long out_size){
  int c = scal[0];
  long M = (long)c*256;
  long stride = (long)gridDim.x*NT;
  for(long i = (long)blockIdx.x*NT + threadIdx.x; i<M; i+=stride){
    float s = part[i] + part[partStride+i] + part[2L*partStride+i] + part[3L*partStride+i];
    if(i < out_size) out[i]=s;
  }
}

// one fp32 atomic per edge into a runtime-KC privatized copy
__global__ void k_edge_pool(const int* __restrict__ row, const int* __restrict__ col,
                            const float* __restrict__ attr, const int* cl,
                            const int* scal, float* dcopies, int E, long CMsq, int KC){
  int c = scal[0];
  float* dc = dcopies + (long)(blockIdx.x % KC)*CMsq;
  int stride = gridDim.x*NT;
  for(int e = blockIdx.x*NT + threadIdx.x; e<E; e+=stride){
    long key = (long)cl[row[e]]*c + cl[col[e]];
    if(key < CMsq){
      unsafeAtomicAdd(&dc[key], attr[e]);
    }
  }
}

__global__ void k_reduce_dense(const float* __restrict__ dcopies, float* dense,
                               const int* scal, long CMsq, int KC){
  long c = scal[0];
  long M = c*c; if(M>CMsq) M=CMsq;
  long stride = (long)gridDim.x*NT;
  for(long i = (long)blockIdx.x*NT + threadIdx.x; i<M; i+=stride){
    float s = dcopies[i];
    for(int k=1;k<KC;k++) s += dcopies[(long)k*CMsq + i];
    dense[i]=s;
  }
}

__device__ __forceinline__ int cellp(const float* dense, long i){
  return __float_as_uint(dense[i]) != SENT;
}

__global__ void k_cscan1(const float* dense, const int* scal, int* bsum, long CMsq){
  int c = scal[0];
  long M = (long)c*c; if(M>CMsq) M=CMsq;
  int t = threadIdx.x;
  long base = (long)blockIdx.x*SCAN_IPB + (long)t*SCAN_T;
  int s = 0;
  if(base < M && c > 0){
    int r = (int)(base / c);
    int q = (int)(base - (long)r*c);
    for(int j=0;j<SCAN_T;j++){
      long i=base+j;
      if(i<M){
        if(cellp(dense,i) && r!=q) s++;
      }
      if(++q==c){ q=0; r++; }
    }
  }
  __shared__ int sh[NT];
  sh[t]=s; __syncthreads();
  for(int off=NT/2; off>0; off>>=1){ if(t<off) sh[t]+=sh[t+off]; __syncthreads(); }
  if(t==0) bsum[blockIdx.x]=sh[0];
}

__global__ void k_cemit(const float* dense, const int* scal,
                        const int* bscan, float* out, long out_size, long CMsq){
  int c = scal[0]; int P = scal[2];
  long M = (long)c*c; if(M>CMsq) M=CMsq;
  long xoff = (long)c*256;
  int t = threadIdx.x;
  long base = (long)blockIdx.x*SCAN_IPB + (long)t*SCAN_T;
  int s = 0;
  int r0=0,q0=0;
  if(base < M && c > 0){
    r0 = (int)(base / c);
    q0 = (int)(base - (long)r0*c);
    int r=r0, q=q0;
    for(int j=0;j<SCAN_T;j++){
      long i=base+j;
      if(i<M){
        if(cellp(dense,i) && r!=q) s++;
      }
      if(++q==c){ q=0; r++; }
    }
  }
  __shared__ int sh[NT];
  sh[t]=s; __syncthreads();
  for(int off=1; off<NT; off<<=1){
    int x=0; if(t>=off) x=sh[t-off];
    __syncthreads();
    sh[t]+=x; __syncthreads();
  }
  int run = bscan[blockIdx.x] + (sh[t]-s);
  if(base < M && c > 0){
    int r=r0, q=q0;
    for(int j=0;j<SCAN_T;j++){
      long i=base+j;
      if(i<M && cellp(dense,i) && r!=q){
        long o0 = xoff + run;
        long o1 = xoff + (long)P + run;
        long o2 = xoff + 2L*(long)P + run;
        if(o0<out_size) out[o0]=(float)r;
        if(o1<out_size) out[o1]=(float)q;
        if(o2<out_size) out[o2]=dense[i];
        run++;
      }
      if(++q==c){ q=0; r++; }
    }
  }
}

// ---------- host ----------

extern "C" void kernel_launch(void* const* d_in, const int* in_sizes, int n_in,
                              void* d_out, int out_size, void* d_ws, size_t ws_size,
                              hipStream_t stream){
  (void)n_in;
  const float* x     = (const float*)d_in[0];
  const int*   eidx  = (const int*)d_in[1];
  const float* eattr = (const float*)d_in[2];
  const int D = 256;
  int n = in_sizes[0]/D;
  int E = in_sizes[1]/2;
  const int* row = eidx;
  const int* col = eidx + E;
  int nwords = (n+31)>>5;
  int CU_B = out_size/256 + 1; if(CU_B > n) CU_B = n;

  char* p = (char*)d_ws;
  auto alloc = [&](size_t bytes)->char*{ char* r=p; p += (bytes+255)&~(size_t)255; return r; };
  int2* LA   = (int2*)alloc((size_t)E*8);
  int2* LB   = (int2*)alloc((size_t)E*8);
  int* a     = (int*)alloc((size_t)n*4);
  int* b     = (int*)alloc((size_t)n*4);
  int* cl    = (int*)alloc((size_t)n*4);
  int* nodeList = (int*)alloc((size_t)n*4);
  int* pref  = (int*)alloc((size_t)n*4);
  int* U1    = (int*)alloc((size_t)n*4);
  int* U2    = (int*)alloc((size_t)n*4);
  int* bsum  = (int*)alloc(4096*4);
  int* bscan = (int*)alloc(4096*4);
  char* zstart = p;                         // zeroed each call
  int* cover   = (int*)alloc((size_t)n*4);
  int* d2      = (int*)alloc((size_t)n*4);
  unsigned int* misb    = (unsigned int*)alloc((size_t)nwords*4);
  unsigned int* reach1b = (unsigned int*)alloc((size_t)nwords*4);
  int* present = (int*)alloc((size_t)n*4);
  int* ccount  = (int*)alloc((size_t)n*4);
  int* cursor  = (int*)alloc((size_t)n*4);
  int* rcnt    = (int*)alloc((MAX_ROUND+2)*4);
  int* lcnt    = (int*)alloc((MAX_ROUND+2)*4);
  int* scal    = (int*)alloc(64);              // [0]=c, [1]=U, [2]=P
  size_t zbytes = (size_t)(p - zstart);

  long partStride = (long)CU_B*256;
  float* part = (float*)alloc((size_t)4*partStride*4);

  size_t used   = (size_t)(p-(char*)d_ws);
  size_t remain = (ws_size > used+4096) ? ws_size-used-4096 : 0;
  long CM = CU_B;
  long CMsq = CM*CM;
  int KC = (int)(remain/(4*(size_t)CMsq)) - 1;
  if(KC > 8) KC = 8;
  if(KC < 1){
    KC = 1;
    while(CM>1 && (size_t)(KC+1)*CM*CM*4 > remain) CM--;
    CMsq = CM*CM;
  }
  float* dcopies = (float*)alloc((size_t)KC*CMsq*4);
  float* dense   = (float*)alloc((size_t)CMsq*4);

  hipMemsetAsync(zstart, 0, zbytes, stream);

  int NB  = (n+NT-1)/NT;
  int NBs = (n+SCAN_IPB-1)/SCAN_IPB;
  int NBc = (CU_B+SCAN_IPB-1)/SCAN_IPB;
  int CB  = (int)((CMsq+SCAN_IPB-1)/SCAN_IPB);
  if(CB>4096) CB=4096;

  // ---- round 0 (full graph, 100% occupancy grids) ----
  k_init    <<<NB,NT,0,stream>>>(a,b,n);
  k_hop0    <<<EG0,NT,0,stream>>>(b,row,col,E);
  k_hop0f   <<<EG0,NT,0,stream>>>(a,b,row,col,n,E);
  k_dil0    <<<EG0,NT,0,stream>>>(a,d2,cover,row,col,E,1);
  k_dil20   <<<EG0,NT,0,stream>>>(a,d2,cover,row,col,E,1);
  k_fincomp0<<<EG0,NT,0,stream>>>(a,b,misb,cover,n,row,col,E,LB,&lcnt[1],U1,&rcnt[0]);

  // ---- rounds 1..MAX_ROUND-1 (compacted, gated; big grids for rounds 1-2) ----
  for(int r=1; r<MAX_ROUND; ++r){
    int2* Ls = (r&1) ? LB : LA;
    int2* Ld = (r&1) ? LA : LB;
    int*  Us = (r&1) ? U1 : U2;
    int*  Ud = (r&1) ? U2 : U1;
    int ep = r+1;
    int G = (r<=2) ? EG1B : EG1;
    k_hop1    <<<G,NT,0,stream>>>(b,a,Ls,&lcnt[r],&rcnt[r-1]);
    k_hop1f   <<<G,NT,0,stream>>>(a,b,Ls,&lcnt[r],Us,&rcnt[r-1],&rcnt[r-1]);
    k_dil11   <<<G,NT,0,stream>>>(a,d2,cover,misb,Ls,&lcnt[r],Us,&rcnt[r-1],&rcnt[r-1],ep);
    k_dil21   <<<G,NT,0,stream>>>(a,d2,cover,Ls,&lcnt[r],&rcnt[r-1],ep);
    k_fincomp1<<<G,NT,0,stream>>>(a,b,cover,n,Ls,&lcnt[r],Ld,&lcnt[r+1],
                                  Us,&rcnt[r-1],Ud,&rcnt[r],&rcnt[r-1]);
  }

  // ---- cluster propagation (bitmask-filtered) ----
  k_cluster_init<<<NB,NT,0,stream>>>(misb,reach1b,a,b,n);
  k_chop1 <<<EG0,NT,0,stream>>>(b,misb,reach1b,row,col,E);
  k_chop2f<<<EG0,NT,0,stream>>>(a,b,reach1b,row,col,n,E);

  // ---- unique -> cluster ids ----
  k_mark <<<NB,NT,0,stream>>>(a,misb,present,scal,n);
  k_scan1<<<NBs,NT,0,stream>>>(present,n,bsum);
  k_scan2<<<1,NT,0,stream>>>(bsum,bscan,NBs,scal+1);
  k_scan3<<<NBs,NT,0,stream>>>(present,n,bscan,pref);
  k_assign<<<NB,NT,0,stream>>>(a,pref,cl,ccount,n);

  // ---- fill privatized dense copies ----
  k_fill_dense<<<2048,NT,0,stream>>>(dcopies,scal,CMsq,KC);

  // ---- counting sort by cluster ----
  k_scan1<<<NBc,NT,0,stream>>>(ccount,CU_B,bsum);
  k_scan2<<<1,NT,0,stream>>>(bsum,bscan,NBc,nullptr);
  k_scan3<<<NBc,NT,0,stream>>>(ccount,CU_B,bscan,pref);
  k_scatter_nodes<<<NB,NT,0,stream>>>(cl,pref,cursor,nodeList,n);

  // ---- x_pooled: 4-segment partials + add ----
  k_pool_seg<<<2048,NT,0,stream>>>(x,nodeList,pref,ccount,scal,part,partStride);
  k_pool_add<<<256,NT,0,stream>>>(part,partStride,scal,(float*)d_out,(long)out_size);

  // ---- pooled adjacency ----
  k_edge_pool<<<EGP,NT,0,stream>>>(row,col,eattr,cl,scal,dcopies,E,CMsq,KC);
  k_reduce_dense<<<1024,NT,0,stream>>>(dcopies,dense,scal,CMsq,KC);
  k_cscan1<<<CB,NT,0,stream>>>(dense,scal,bsum,CMsq);
  k_scan2 <<<1,NT,0,stream>>>(bsum,bscan,CB,scal+2);
  k_cemit <<<CB,NT,0,stream>>>(dense,scal,bscan,(float*)d_out,(long)out_size,CMsq);
}

// Round 15
// 1672.196 us; speedup vs baseline: 1.2090x; 1.0328x over previous
//
#include <hip/hip_runtime.h>
#include <cmath>
#include <cstdint>

#define NT 256
#define EG0 2048
#define EGP 1024
#define EG1 256
#define EG1B 1024
#define MAX_ROUND 16
#define SCAN_T 32
#define SCAN_IPB (NT*SCAN_T)
#define SENT 0x80000000u

// ---------- helpers ----------

__device__ __forceinline__ int getbit(const unsigned int* bm, int v){
  return (bm[v>>5]>>(v&31))&1u;
}
__device__ __forceinline__ void setbit(unsigned int* bm, int v){
  unsigned int m = 1u<<(v&31);
  if(!(bm[v>>5]&m)) atomicOr(&bm[v>>5], m);
}

__device__ __forceinline__ int block_append(int* cursor, bool pred, int* s_w){
  int wid  = threadIdx.x >> 6;
  int lane = threadIdx.x & 63;
  unsigned long long m = __ballot(pred);
  int cnt = __popcll(m);
  if(lane==0) s_w[wid]=cnt;
  __syncthreads();
  if(threadIdx.x==0){
    int t0=s_w[0], t1=s_w[1], t2=s_w[2], t3=s_w[3];
    int tot=t0+t1+t2+t3;
    int base = tot ? atomicAdd(cursor, tot) : 0;
    s_w[0]=base; s_w[1]=base+t0; s_w[2]=base+t0+t1; s_w[3]=base+t0+t1+t2;
  }
  __syncthreads();
  int pos = s_w[wid] + __popcll(m & ((1ull<<lane)-1ull));
  __syncthreads();
  return pos;
}

// ---------- init ----------

__global__ void k_init(int* a, int* b, int n){
  int v = blockIdx.x*NT + threadIdx.x;
  if(v<n){ a[v]=v; b[v]=v; }
}

__global__ void k_fill_dense(float* dcopies, const int* scal, long CMsq, int KC){
  long c = scal[0];
  long M = c*c; if(M>CMsq) M=CMsq;
  long stride = (long)gridDim.x*NT;
  for(long i = (long)blockIdx.x*NT + threadIdx.x; i<M; i+=stride){
    for(int k=0;k<KC;k++)
      ((unsigned int*)dcopies)[(long)k*CMsq + i] = SENT;
  }
}

// word-owner new-MIS bitmask build: no atomics (thread w owns word w)
__global__ void k_newmis(const int* a, unsigned int* nmb, int nwords, int n){
  int w = blockIdx.x*NT + threadIdx.x;
  if(w<nwords){
    unsigned int m = 0;
    int base = w<<5;
    int lim = n - base; if(lim>32) lim=32;
    for(int j=0;j<lim;j++){
      int v = base+j;
      if(a[v]==v) m |= 1u<<j;
    }
    nmb[w]=m;
  }
}

// ---------- round 0 (full edge arrays) ----------

// b[col] min= row, b[col] <= col invariant => row>=col is a no-op: skip gather+atomic
__global__ void k_hop0(int* b, const int* __restrict__ row,
                       const int* __restrict__ col, int E){
  int stride = gridDim.x*NT;
  for(int e = blockIdx.x*NT + threadIdx.x; e<E; e+=stride){
    int s = row[e], c = col[e];
    if(s < c && s < b[c]) atomicMin(&b[c], s);
  }
}

// a[col] <= col invariant => s>=col is a no-op: skip a-gather+atomic
__global__ void k_hop0f(int* a, const int* b, const int* __restrict__ row,
                        const int* __restrict__ col, int n, int E){
  int stride = gridDim.x*NT;
  int total = n + E;
  for(int i = blockIdx.x*NT + threadIdx.x; i<total; i+=stride){
    if(i<n){
      if(b[i] < a[i]) atomicMin(&a[i], b[i]);
    } else {
      int e = i-n;
      int s = b[row[e]];
      int c = col[e];
      if(s < c && s < a[c]) atomicMin(&a[c], s);
    }
  }
}

// dil1: new-MIS rows (L1-resident bitmask) seed d2 (epoch) + cover; plain stores
__global__ void k_dil0(const unsigned int* __restrict__ nmb, int* d2, int* cover,
                       const int* __restrict__ row, const int* __restrict__ col,
                       int E, int ep){
  int stride = gridDim.x*NT;
  for(int e = blockIdx.x*NT + threadIdx.x; e<E; e+=stride){
    int r = row[e];
    if(getbit(nmb,r)){
      int cc = col[e];
      d2[r]=ep;  cover[r]=1;
      d2[cc]=ep; cover[cc]=1;
    }
  }
}

// dil2: d2[r]==ep subsumes new-MIS check (dil0 set it on the same edge list)
__global__ void k_dil20(const int* d2, int* cover, const int* __restrict__ row,
                        const int* __restrict__ col, int E, int ep){
  int stride = gridDim.x*NT;
  for(int e = blockIdx.x*NT + threadIdx.x; e<E; e+=stride){
    if(d2[row[e]]==ep && !cover[col[e]]) cover[col[e]]=1;
  }
}

__global__ void k_fincomp0(int* a, int* b, unsigned int* misb, int* cover, int n,
                           const int* __restrict__ row, const int* __restrict__ col, int E,
                           int2* Ld, int* lcnt1, int* U1, int* rcnt0){
  __shared__ int s_w[4];
  long nth = (long)gridDim.x*NT;
  for(long base = (long)blockIdx.x*NT; base < n; base += nth){
    int v = (int)base + threadIdx.x;
    bool unc = false;
    if(v<n){
      int nw = (a[v]==v);
      if(nw){ setbit(misb,v); if(!cover[v]) cover[v]=1; }
      int cov = cover[v] | nw;
      int val = cov ? n : v;
      a[v]=val; b[v]=val;
      unc = !cov;
    }
    int pos = block_append(rcnt0, unc, s_w);
    if(unc) U1[pos]=v;
  }
  for(long base = (long)blockIdx.x*NT; base < E; base += nth){
    int e = (int)base + threadIdx.x;
    bool keep=false; int2 ed;
    if(e<E){
      ed = make_int2(row[e], col[e]);
      keep = (!cover[ed.x]) || (!cover[ed.y]);
    }
    int pos = block_append(lcnt1, keep, s_w);
    if(keep) Ld[pos]=ed;
  }
}

// ---------- rounds >=1 (compacted, gated) ----------

__global__ void k_hop1(int* b, const int* a, const int2* L, const int* pE,
                       const int* gate){
  if(*gate==0) return;
  int E = *pE;
  int stride = gridDim.x*NT;
  for(int e = blockIdx.x*NT + threadIdx.x; e<E; e+=stride){
    int2 ed = L[e];
    int s = a[ed.x];
    if(s < b[ed.y]) atomicMin(&b[ed.y], s);
  }
}

__global__ void k_hop1f(int* a, const int* b, const int2* L, const int* pE,
                        const int* U, const int* pU, const int* gate){
  if(*gate==0) return;
  int E = *pE, un = *pU;
  int total = un + E;
  int stride = gridDim.x*NT;
  for(int i = blockIdx.x*NT + threadIdx.x; i<total; i+=stride){
    if(i<un){
      int u = U[i];
      if(b[u] < a[u]) atomicMin(&a[u], b[u]);
    } else {
      int2 ed = L[i-un];
      int s = b[ed.x];
      if(s < a[ed.y]) atomicMin(&a[ed.y], s);
    }
  }
}

__global__ void k_dil11(const int* a, int* d2, int* cover, unsigned int* misb,
                        const int2* L, const int* pE, const int* U, const int* pU,
                        const int* gate, int ep){
  if(*gate==0) return;
  int E = *pE, un = *pU;
  int total = un + E;
  int stride = gridDim.x*NT;
  for(int i = blockIdx.x*NT + threadIdx.x; i<total; i+=stride){
    if(i<un){
      int u = U[i];
      if(a[u]==u){ setbit(misb,u); cover[u]=1; d2[u]=ep; }
    } else {
      int2 ed = L[i-un];
      if(a[ed.x]==ed.x){ d2[ed.x]=ep; cover[ed.x]=1; d2[ed.y]=ep; cover[ed.y]=1; }
    }
  }
}

// d2[x]==ep subsumes the new-MIS check (dil11 iterates the same list)
__global__ void k_dil21(const int* d2, int* cover, const int2* L,
                        const int* pE, const int* gate, int ep){
  if(*gate==0) return;
  int E = *pE;
  int stride = gridDim.x*NT;
  for(int e = blockIdx.x*NT + threadIdx.x; e<E; e+=stride){
    int2 ed = L[e];
    if(d2[ed.x]==ep && !cover[ed.y]) cover[ed.y]=1;
  }
}

__global__ void k_fincomp1(int* a, int* b, const int* cover, int n,
                           const int2* Ls, const int* pE, int2* Ld, int* lcntD,
                           const int* Us, const int* pU, int* Ud, int* rcntD,
                           const int* gate){
  if(*gate==0) return;
  __shared__ int s_w[4];
  int E = *pE, un = *pU;
  long nth = (long)gridDim.x*NT;
  for(long base = (long)blockIdx.x*NT; base < un; base += nth){
    int i = (int)base + threadIdx.x;
    bool unc=false; int u=0;
    if(i<un){ u = Us[i]; unc = !cover[u]; }
    int pos = block_append(rcntD, unc, s_w);
    if(unc) Ud[pos]=u;
  }
  for(long base = (long)blockIdx.x*NT; base < E; base += nth){
    int e = (int)base + threadIdx.x;
    bool keep=false; int2 ed;
    if(e<E){
      ed = Ls[e];
      int vx = cover[ed.x] ? n : ed.x;  a[ed.x]=vx; b[ed.x]=vx;
      int vy = cover[ed.y] ? n : ed.y;  a[ed.y]=vy; b[ed.y]=vy;
      keep = (!cover[ed.x]) || (!cover[ed.y]);
    }
    int pos = block_append(lcntD, keep, s_w);
    if(keep) Ld[pos]=ed;
  }
}

// ---------- cluster phase (bitmask-filtered) ----------

__global__ void k_cluster_init(const unsigned int* misb, unsigned int* reach1b,
                               int* a, int* b, int n){
  int v = blockIdx.x*NT + threadIdx.x;
  if(v<n){
    int m = getbit(misb,v);
    int val = m ? v : n;
    a[v]=val; b[v]=val;
    if(m) setbit(reach1b,v);
  }
}

__global__ void k_chop1(int* b, const unsigned int* misb, unsigned int* reach1b,
                        const int* __restrict__ row, const int* __restrict__ col, int E){
  int stride = gridDim.x*NT;
  for(int e = blockIdx.x*NT + threadIdx.x; e<E; e+=stride){
    int r = row[e];
    if(getbit(misb,r)){
      int cc = col[e];
      if(r < b[cc]) atomicMin(&b[cc], r);
      setbit(reach1b, cc);
    }
  }
}

__global__ void k_chop2f(int* a, const int* b, const unsigned int* reach1b,
                         const int* __restrict__ row, const int* __restrict__ col,
                         int n, int E){
  int stride = gridDim.x*NT;
  int total = n + E;
  for(int i = blockIdx.x*NT + threadIdx.x; i<total; i+=stride){
    if(i<n){
      if(b[i] < a[i]) atomicMin(&a[i], b[i]);
    } else {
      int e = i-n;
      int r = row[e];
      if(getbit(reach1b,r)){
        int s = b[r];
        if(s < n && s < a[col[e]]) atomicMin(&a[col[e]], s);
      }
    }
  }
}

__global__ void k_mark(const int* mr, const unsigned int* misb, int* present, int* cmis, int n){
  int v = blockIdx.x*NT + threadIdx.x;
  int m = 0;
  if(v<n){
    int r = mr[v];
    if(r<n && !present[r]) present[r]=1;
    m = getbit(misb,v);
  }
  __shared__ int sh[NT];
  sh[threadIdx.x]=m; __syncthreads();
  for(int off=NT/2; off>0; off>>=1){
    if(threadIdx.x<off) sh[threadIdx.x]+=sh[threadIdx.x+off];
    __syncthreads();
  }
  if(threadIdx.x==0 && sh[0]) atomicAdd(cmis, sh[0]);
}

// ---------- generic scan ----------

__global__ void k_scan1(const int* A, int M, int* bsum){
  int t = threadIdx.x;
  long base = (long)blockIdx.x*SCAN_IPB + (long)t*SCAN_T;
  int s = 0;
  #pragma unroll
  for(int j=0;j<SCAN_T;j++){ long i=base+j; if(i<M) s += A[i]; }
  __shared__ int sh[NT];
  sh[t]=s; __syncthreads();
  for(int off=NT/2; off>0; off>>=1){ if(t<off) sh[t]+=sh[t+off]; __syncthreads(); }
  if(t==0) bsum[blockIdx.x]=sh[0];
}

__global__ void k_scan2(const int* bsum, int* bscan, int B, int* totalOut){
  __shared__ int sh[NT];
  int t = threadIdx.x;
  int carry = 0;
  for(int base=0; base<B; base+=NT){
    int i = base+t;
    int v = (i<B) ? bsum[i] : 0;
    sh[t]=v; __syncthreads();
    for(int off=1; off<NT; off<<=1){
      int x=0; if(t>=off) x=sh[t-off];
      __syncthreads();
      sh[t]+=x; __syncthreads();
    }
    int incl = sh[t];
    if(i<B) bscan[i] = carry + incl - v;
    carry += sh[NT-1];
    __syncthreads();
  }
  if(t==0 && totalOut) *totalOut = carry;
}

__global__ void k_scan3(const int* A, int M, const int* bscan, int* pref){
  int t = threadIdx.x;
  long base = (long)blockIdx.x*SCAN_IPB + (long)t*SCAN_T;
  int s = 0;
  #pragma unroll
  for(int j=0;j<SCAN_T;j++){ long i=base+j; if(i<M) s += A[i]; }
  __shared__ int sh[NT];
  sh[t]=s; __syncthreads();
  for(int off=1; off<NT; off<<=1){
    int x=0; if(t>=off) x=sh[t-off];
    __syncthreads();
    sh[t]+=x; __syncthreads();
  }
  int run = bscan[blockIdx.x] + (sh[t]-s);
  for(int j=0;j<SCAN_T;j++){
    long i=base+j;
    if(i<M){ pref[i]=run; run += A[i]; }
  }
}

// ---------- clustering & pooling ----------

__global__ void k_assign(const int* mr, const int* pref, int* cl, int* ccount, int n){
  int v = blockIdx.x*NT + threadIdx.x;
  if(v<n){
    int r = mr[v];
    int cid = (r<n) ? pref[r] : 0;
    cl[v]=cid;
    atomicAdd(&ccount[cid],1);
  }
}

__global__ void k_scatter_nodes(const int* cl, const int* cstart, int* cursor, int* nodeList, int n){
  int v = blockIdx.x*NT + threadIdx.x;
  if(v<n){
    int cid = cl[v];
    int pos = cstart[cid] + atomicAdd(&cursor[cid],1);
    nodeList[pos]=v;
  }
}

__global__ void k_pool_seg(const float* __restrict__ x, const int* nodeList, const int* cstart,
                           const int* ccount, const int* scal, float* part, long partStride){
  int c = scal[0], U = scal[1];
  int t = threadIdx.x;
  int total = c*4;
  for(int idx = blockIdx.x; idx < total; idx += gridDim.x){
    int cid = idx>>2, seg = idx&3;
    float s0=0.f,s1=0.f,s2=0.f,s3=0.f,s4=0.f,s5=0.f,s6=0.f,s7=0.f;
    if(cid<U){
      int st = cstart[cid], cn = ccount[cid];
      int q  = (cn+3)>>2;
      int lo = seg*q, hi = lo+q; if(hi>cn) hi=cn;
      int i=lo;
      for(; i+7<hi; i+=8){
        int n0=nodeList[st+i],   n1=nodeList[st+i+1], n2=nodeList[st+i+2], n3=nodeList[st+i+3];
        int n4=nodeList[st+i+4], n5=nodeList[st+i+5], n6=nodeList[st+i+6], n7=nodeList[st+i+7];
        s0 += x[(size_t)n0*256 + t]; s1 += x[(size_t)n1*256 + t];
        s2 += x[(size_t)n2*256 + t]; s3 += x[(size_t)n3*256 + t];
        s4 += x[(size_t)n4*256 + t]; s5 += x[(size_t)n5*256 + t];
        s6 += x[(size_t)n6*256 + t]; s7 += x[(size_t)n7*256 + t];
      }
      for(; i<hi; i++) s0 += x[(size_t)nodeList[st+i]*256 + t];
      s0 += s1+s2+s3+s4+s5+s6+s7;
    }
    part[(long)seg*partStride + (long)cid*256 + t] = s0;
  }
}

__global__ void k_pool_add(const float* __restrict__ part, long partStride,
                           const int* scal, float* out, long out_size){
  int c = scal[0];
  long M = (long)c*256;
  long stride = (long)gridDim.x*NT;
  for(long i = (long)blockIdx.x*NT + threadIdx.x; i<M; i+=stride){
    float s = part[i] + part[partStride+i] + part[2L*partStride+i] + part[3L*partStride+i];
    if(i < out_size) out[i]=s;
  }
}

__global__ void k_edge_pool(const int* __restrict__ row, const int* __restrict__ col,
                            const float* __restrict__ attr, const int* cl,
                            const int* scal, float* dcopies, int E, long CMsq, int KC){
  int c = scal[0];
  float* dc = dcopies + (long)(blockIdx.x % KC)*CMsq;
  int stride = gridDim.x*NT;
  for(int e = blockIdx.x*NT + threadIdx.x; e<E; e+=stride){
    long key = (long)cl[row[e]]*c + cl[col[e]];
    if(key < CMsq){
      unsafeAtomicAdd(&dc[key], attr[e]);
    }
  }
}

__global__ void k_reduce_dense(const float* __restrict__ dcopies, float* dense,
                               const int* scal, long CMsq, int KC){
  long c = scal[0];
  long M = c*c; if(M>CMsq) M=CMsq;
  long stride = (long)gridDim.x*NT;
  for(long i = (long)blockIdx.x*NT + threadIdx.x; i<M; i+=stride){
    float s = dcopies[i];
    for(int k=1;k<KC;k++) s += dcopies[(long)k*CMsq + i];
    dense[i]=s;
  }
}

__device__ __forceinline__ int cellp(const float* dense, long i){
  return __float_as_uint(dense[i]) != SENT;
}

__global__ void k_cscan1(const float* dense, const int* scal, int* bsum, long CMsq){
  int c = scal[0];
  long M = (long)c*c; if(M>CMsq) M=CMsq;
  int t = threadIdx.x;
  long base = (long)blockIdx.x*SCAN_IPB + (long)t*SCAN_T;
  int s = 0;
  if(base < M && c > 0){
    int r = (int)(base / c);
    int q = (int)(base - (long)r*c);
    for(int j=0;j<SCAN_T;j++){
      long i=base+j;
      if(i<M){
        if(cellp(dense,i) && r!=q) s++;
      }
      if(++q==c){ q=0; r++; }
    }
  }
  __shared__ int sh[NT];
  sh[t]=s; __syncthreads();
  for(int off=NT/2; off>0; off>>=1){ if(t<off) sh[t]+=sh[t+off]; __syncthreads(); }
  if(t==0) bsum[blockIdx.x]=sh[0];
}

__global__ void k_cemit(const float* dense, const int* scal,
                        const int* bscan, float* out, long out_size, long CMsq){
  int c = scal[0]; int P = scal[2];
  long M = (long)c*c; if(M>CMsq) M=CMsq;
  long xoff = (long)c*256;
  int t = threadIdx.x;
  long base = (long)blockIdx.x*SCAN_IPB + (long)t*SCAN_T;
  int s = 0;
  int r0=0,q0=0;
  if(base < M && c > 0){
    r0 = (int)(base / c);
    q0 = (int)(base - (long)r0*c);
    int r=r0, q=q0;
    for(int j=0;j<SCAN_T;j++){
      long i=base+j;
      if(i<M){
        if(cellp(dense,i) && r!=q) s++;
      }
      if(++q==c){ q=0; r++; }
    }
  }
  __shared__ int sh[NT];
  sh[t]=s; __syncthreads();
  for(int off=1; off<NT; off<<=1){
    int x=0; if(t>=off) x=sh[t-off];
    __syncthreads();
    sh[t]+=x; __syncthreads();
  }
  int run = bscan[blockIdx.x] + (sh[t]-s);
  if(base < M && c > 0){
    int r=r0, q=q0;
    for(int j=0;j<SCAN_T;j++){
      long i=base+j;
      if(i<M && cellp(dense,i) && r!=q){
        long o0 = xoff + run;
        long o1 = xoff + (long)P + run;
        long o2 = xoff + 2L*(long)P + run;
        if(o0<out_size) out[o0]=(float)r;
        if(o1<out_size) out[o1]=(float)q;
        if(o2<out_size) out[o2]=dense[i];
        run++;
      }
      if(++q==c){ q=0; r++; }
    }
  }
}

// ---------- host ----------

extern "C" void kernel_launch(void* const* d_in, const int* in_sizes, int n_in,
                              void* d_out, int out_size, void* d_ws, size_t ws_size,
                              hipStream_t stream){
  (void)n_in;
  const float* x     = (const float*)d_in[0];
  const int*   eidx  = (const int*)d_in[1];
  const float* eattr = (const float*)d_in[2];
  const int D = 256;
  int n = in_sizes[0]/D;
  int E = in_sizes[1]/2;
  const int* row = eidx;
  const int* col = eidx + E;
  int nwords = (n+31)>>5;
  int CU_B = out_size/256 + 1; if(CU_B > n) CU_B = n;

  char* p = (char*)d_ws;
  auto alloc = [&](size_t bytes)->char*{ char* r=p; p += (bytes+255)&~(size_t)255; return r; };
  int2* LA   = (int2*)alloc((size_t)E*8);
  int2* LB   = (int2*)alloc((size_t)E*8);
  int* a     = (int*)alloc((size_t)n*4);
  int* b     = (int*)alloc((size_t)n*4);
  int* cl    = (int*)alloc((size_t)n*4);
  int* nodeList = (int*)alloc((size_t)n*4);
  int* pref  = (int*)alloc((size_t)n*4);
  int* U1    = (int*)alloc((size_t)n*4);
  int* U2    = (int*)alloc((size_t)n*4);
  int* bsum  = (int*)alloc(4096*4);
  int* bscan = (int*)alloc(4096*4);
  unsigned int* nmb = (unsigned int*)alloc((size_t)nwords*4);   // new-MIS bitmask (round 0)
  char* zstart = p;                         // zeroed each call
  int* cover   = (int*)alloc((size_t)n*4);
  int* d2      = (int*)alloc((size_t)n*4);
  unsigned int* misb    = (unsigned int*)alloc((size_t)nwords*4);
  unsigned int* reach1b = (unsigned int*)alloc((size_t)nwords*4);
  int* present = (int*)alloc((size_t)n*4);
  int* ccount  = (int*)alloc((size_t)n*4);
  int* cursor  = (int*)alloc((size_t)n*4);
  int* rcnt    = (int*)alloc((MAX_ROUND+2)*4);
  int* lcnt    = (int*)alloc((MAX_ROUND+2)*4);
  int* scal    = (int*)alloc(64);              // [0]=c, [1]=U, [2]=P
  size_t zbytes = (size_t)(p - zstart);

  long partStride = (long)CU_B*256;
  float* part = (float*)alloc((size_t)4*partStride*4);

  size_t used   = (size_t)(p-(char*)d_ws);
  size_t remain = (ws_size > used+4096) ? ws_size-used-4096 : 0;
  long CM = CU_B;
  long CMsq = CM*CM;
  int KC = (int)(remain/(4*(size_t)CMsq)) - 1;
  if(KC > 8) KC = 8;
  if(KC < 1){
    KC = 1;
    while(CM>1 && (size_t)(KC+1)*CM*CM*4 > remain) CM--;
    CMsq = CM*CM;
  }
  float* dcopies = (float*)alloc((size_t)KC*CMsq*4);
  float* dense   = (float*)alloc((size_t)CMsq*4);

  hipMemsetAsync(zstart, 0, zbytes, stream);

  int NB  = (n+NT-1)/NT;
  int NWB = (nwords+NT-1)/NT;
  int NBs = (n+SCAN_IPB-1)/SCAN_IPB;
  int NBc = (CU_B+SCAN_IPB-1)/SCAN_IPB;
  int CB  = (int)((CMsq+SCAN_IPB-1)/SCAN_IPB);
  if(CB>4096) CB=4096;

  // ---- round 0 (full graph) ----
  k_init    <<<NB,NT,0,stream>>>(a,b,n);
  k_hop0    <<<EG0,NT,0,stream>>>(b,row,col,E);
  k_hop0f   <<<EG0,NT,0,stream>>>(a,b,row,col,n,E);
  k_newmis  <<<NWB,NT,0,stream>>>(a,nmb,nwords,n);
  k_dil0    <<<EG0,NT,0,stream>>>(nmb,d2,cover,row,col,E,1);
  k_dil20   <<<EG0,NT,0,stream>>>(d2,cover,row,col,E,1);
  k_fincomp0<<<EG0,NT,0,stream>>>(a,b,misb,cover,n,row,col,E,LB,&lcnt[1],U1,&rcnt[0]);

  // ---- rounds 1..MAX_ROUND-1 (compacted, gated) ----
  for(int r=1; r<MAX_ROUND; ++r){
    int2* Ls = (r&1) ? LB : LA;
    int2* Ld = (r&1) ? LA : LB;
    int*  Us = (r&1) ? U1 : U2;
    int*  Ud = (r&1) ? U2 : U1;
    int ep = r+1;
    int G = (r<=2) ? EG1B : EG1;
    k_hop1    <<<G,NT,0,stream>>>(b,a,Ls,&lcnt[r],&rcnt[r-1]);
    k_hop1f   <<<G,NT,0,stream>>>(a,b,Ls,&lcnt[r],Us,&rcnt[r-1],&rcnt[r-1]);
    k_dil11   <<<G,NT,0,stream>>>(a,d2,cover,misb,Ls,&lcnt[r],Us,&rcnt[r-1],&rcnt[r-1],ep);
    k_dil21   <<<G,NT,0,stream>>>(d2,cover,Ls,&lcnt[r],&rcnt[r-1],ep);
    k_fincomp1<<<G,NT,0,stream>>>(a,b,cover,n,Ls,&lcnt[r],Ld,&lcnt[r+1],
                                  Us,&rcnt[r-1],Ud,&rcnt[r],&rcnt[r-1]);
  }

  // ---- cluster propagation (bitmask-filtered) ----
  k_cluster_init<<<NB,NT,0,stream>>>(misb,reach1b,a,b,n);
  k_chop1 <<<EG0,NT,0,stream>>>(b,misb,reach1b,row,col,E);
  k_chop2f<<<EG0,NT,0,stream>>>(a,b,reach1b,row,col,n,E);

  // ---- unique -> cluster ids ----
  k_mark <<<NB,NT,0,stream>>>(a,misb,present,scal,n);
  k_scan1<<<NBs,NT,0,stream>>>(present,n,bsum);
  k_scan2<<<1,NT,0,stream>>>(bsum,bscan,NBs,scal+1);
  k_scan3<<<NBs,NT,0,stream>>>(present,n,bscan,pref);
  k_assign<<<NB,NT,0,stream>>>(a,pref,cl,ccount,n);

  // ---- fill privatized dense copies ----
  k_fill_dense<<<2048,NT,0,stream>>>(dcopies,scal,CMsq,KC);

  // ---- counting sort by cluster ----
  k_scan1<<<NBc,NT,0,stream>>>(ccount,CU_B,bsum);
  k_scan2<<<1,NT,0,stream>>>(bsum,bscan,NBc,nullptr);
  k_scan3<<<NBc,NT,0,stream>>>(ccount,CU_B,bscan,pref);
  k_scatter_nodes<<<NB,NT,0,stream>>>(cl,pref,cursor,nodeList,n);

  // ---- x_pooled: 4-segment partials + add ----
  k_pool_seg<<<2048,NT,0,stream>>>(x,nodeList,pref,ccount,scal,part,partStride);
  k_pool_add<<<256,NT,0,stream>>>(part,partStride,scal,(float*)d_out,(long)out_size);

  // ---- pooled adjacency ----
  k_edge_pool<<<EGP,NT,0,stream>>>(row,col,eattr,cl,scal,dcopies,E,CMsq,KC);
  k_reduce_dense<<<1024,NT,0,stream>>>(dcopies,dense,scal,CMsq,KC);
  k_cscan1<<<CB,NT,0,stream>>>(dense,scal,bsum,CMsq);
  k_scan2 <<<1,NT,0,stream>>>(bsum,bscan,CB,scal+2);
  k_cemit <<<CB,NT,0,stream>>>(dense,scal,bscan,(float*)d_out,(long)out_size,CMsq);
}